// Round 1
// baseline (757.591 us; speedup 1.0000x reference)
//
#include <hip/hip_runtime.h>

#define SDIM 2048
#define CDIM 1024
#define BDIM 4
#define HDIM 16
#define DDIM 64

typedef __attribute__((ext_vector_type(8))) short bf16x8;
typedef __attribute__((ext_vector_type(4))) float f32x4;

__device__ __forceinline__ unsigned short f2b(float f) {
    union { float f; unsigned u; } v; v.f = f;
    unsigned r = v.u + 0x7FFFu + ((v.u >> 16) & 1u);
    return (unsigned short)(r >> 16);
}

// ---------------------------------------------------------------------------
// K1: QKV projection GEMM. X[8192,1024] fp32 @ W[1024,3072] fp32 + b ->
// Q,K,V bf16 in [B,H,S,D] layout. 128x128x32 tiles, 4 waves of 64x64 each.
// ---------------------------------------------------------------------------
__global__ __launch_bounds__(256) void qkv_gemm(
    const float* __restrict__ X, const float* __restrict__ W,
    const float* __restrict__ bias,
    unsigned short* __restrict__ Qb, unsigned short* __restrict__ Kb,
    unsigned short* __restrict__ Vb)
{
    __shared__ __align__(16) unsigned short As[128][40];
    __shared__ __align__(16) unsigned short Bs[128][40];
    const int tid  = threadIdx.x;
    const int lane = tid & 63;
    const int wave = tid >> 6;
    const int wm = wave >> 1, wn = wave & 1;
    const int l16 = lane & 15, quad = lane >> 4;
    const int m0 = blockIdx.y * 128;
    const int n0 = blockIdx.x * 128;
    const int N = 3 * CDIM, K = CDIM;

    f32x4 acc[4][4];
#pragma unroll
    for (int i = 0; i < 4; i++)
#pragma unroll
        for (int j = 0; j < 4; j++) acc[i][j] = (f32x4){0.f, 0.f, 0.f, 0.f};

    for (int k0 = 0; k0 < K; k0 += 32) {
        __syncthreads();
        // stage A: 128x32 fp32 -> bf16
#pragma unroll
        for (int it = 0; it < 4; it++) {
            int c = tid + it * 256;
            int row = c >> 3, col = (c & 7) * 4;
            float4 f = *reinterpret_cast<const float4*>(&X[(size_t)(m0 + row) * K + k0 + col]);
            ushort4 u; u.x = f2b(f.x); u.y = f2b(f.y); u.z = f2b(f.z); u.w = f2b(f.w);
            *reinterpret_cast<ushort4*>(&As[row][col]) = u;
        }
        // stage B transposed: W[k0..k0+32, n0..n0+128] -> Bs[n][k]
#pragma unroll
        for (int it = 0; it < 4; it++) {
            int c = tid + it * 256;
            int krow = c >> 5, nc = (c & 31) * 4;
            float4 f = *reinterpret_cast<const float4*>(&W[(size_t)(k0 + krow) * N + n0 + nc]);
            Bs[nc + 0][krow] = f2b(f.x);
            Bs[nc + 1][krow] = f2b(f.y);
            Bs[nc + 2][krow] = f2b(f.z);
            Bs[nc + 3][krow] = f2b(f.w);
        }
        __syncthreads();

        bf16x8 a[4], b[4];
#pragma unroll
        for (int i = 0; i < 4; i++)
            a[i] = *reinterpret_cast<const bf16x8*>(&As[wm * 64 + i * 16 + l16][quad * 8]);
#pragma unroll
        for (int j = 0; j < 4; j++)
            b[j] = *reinterpret_cast<const bf16x8*>(&Bs[wn * 64 + j * 16 + l16][quad * 8]);
#pragma unroll
        for (int i = 0; i < 4; i++)
#pragma unroll
            for (int j = 0; j < 4; j++)
                acc[i][j] = __builtin_amdgcn_mfma_f32_16x16x32_bf16(a[i], b[j], acc[i][j], 0, 0, 0);
    }

    // epilogue: scatter into Q/K/V [B,H,S,D] bf16
#pragma unroll
    for (int i = 0; i < 4; i++) {
        int mbase = m0 + wm * 64 + i * 16 + quad * 4;
#pragma unroll
        for (int j = 0; j < 4; j++) {
            int n = n0 + wn * 64 + j * 16 + l16;
            float bv = bias[n];
            int which = n >> 10;
            int cc = n & 1023;
            int h = cc >> 6, d = cc & 63;
            unsigned short* dst = (which == 0) ? Qb : ((which == 1) ? Kb : Vb);
#pragma unroll
            for (int r = 0; r < 4; r++) {
                int mm = mbase + r;
                int bb = mm >> 11, s = mm & 2047;
                size_t idx = ((size_t)((bb * HDIM + h) * SDIM + s)) * DDIM + d;
                dst[idx] = f2b(acc[i][j][r] + bv);
            }
        }
    }
}

// ---------------------------------------------------------------------------
// K2: causal flash attention. 1 block = (b,h, 64 q-rows). 4 waves x 16 q-rows.
// ---------------------------------------------------------------------------
__global__ __launch_bounds__(256) void attn(
    const unsigned short* __restrict__ Qb, const unsigned short* __restrict__ Kb,
    const unsigned short* __restrict__ Vb, unsigned short* __restrict__ Ob)
{
    __shared__ __align__(16) unsigned short Qs[64][72];
    __shared__ __align__(16) unsigned short Ks[64][72];
    __shared__ __align__(16) unsigned short Vts[64][72];   // [d][key]
    __shared__ __align__(16) unsigned short Ps[4][16][72]; // per-wave P tile

    const int tid = threadIdx.x;
    const int lane = tid & 63, wave = tid >> 6;
    const int l16 = lane & 15, quad = lane >> 4;
    const int bh = blockIdx.x >> 5;   // b*16+h
    const int qt = blockIdx.x & 31;
    const int q0 = qt * 64;
    const int b = bh >> 4, h = bh & 15;
    const size_t base = (size_t)bh * SDIM * DDIM;

    // load Q tile (64x64 bf16)
#pragma unroll
    for (int it = 0; it < 2; it++) {
        int c = tid + it * 256;
        int row = c >> 3, d8 = (c & 7) * 8;
        *reinterpret_cast<uint4*>(&Qs[row][d8]) =
            *reinterpret_cast<const uint4*>(&Qb[base + (size_t)(q0 + row) * DDIM + d8]);
    }

    f32x4 O[4];
#pragma unroll
    for (int j = 0; j < 4; j++) O[j] = (f32x4){0.f, 0.f, 0.f, 0.f};
    float m_r[4], l_r[4];
#pragma unroll
    for (int r = 0; r < 4; r++) { m_r[r] = -1e30f; l_r[r] = 0.f; }

    const int nkb = qt + 1;
    for (int kbi = 0; kbi < nkb; kbi++) {
        int kb = kbi * 64;
        __syncthreads();
        // stage K rows
#pragma unroll
        for (int it = 0; it < 2; it++) {
            int c = tid + it * 256;
            int row = c >> 3, d8 = (c & 7) * 8;
            *reinterpret_cast<uint4*>(&Ks[row][d8]) =
                *reinterpret_cast<const uint4*>(&Kb[base + (size_t)(kb + row) * DDIM + d8]);
        }
        // stage V transposed: Vts[d][key]
#pragma unroll
        for (int it = 0; it < 2; it++) {
            int c = tid + it * 256;
            int row = c >> 3, d8 = (c & 7) * 8;
            uint4 v = *reinterpret_cast<const uint4*>(&Vb[base + (size_t)(kb + row) * DDIM + d8]);
            const unsigned short* pv = reinterpret_cast<const unsigned short*>(&v);
#pragma unroll
            for (int e = 0; e < 8; e++) Vts[d8 + e][row] = pv[e];
        }
        __syncthreads();

        // QK^T: 16 q-rows x 64 keys per wave
        bf16x8 aq0 = *reinterpret_cast<const bf16x8*>(&Qs[wave * 16 + l16][quad * 8]);
        bf16x8 aq1 = *reinterpret_cast<const bf16x8*>(&Qs[wave * 16 + l16][32 + quad * 8]);
        f32x4 sc[4];
#pragma unroll
        for (int j = 0; j < 4; j++) {
            bf16x8 bk0 = *reinterpret_cast<const bf16x8*>(&Ks[j * 16 + l16][quad * 8]);
            bf16x8 bk1 = *reinterpret_cast<const bf16x8*>(&Ks[j * 16 + l16][32 + quad * 8]);
            f32x4 s = (f32x4){0.f, 0.f, 0.f, 0.f};
            s = __builtin_amdgcn_mfma_f32_16x16x32_bf16(aq0, bk0, s, 0, 0, 0);
            s = __builtin_amdgcn_mfma_f32_16x16x32_bf16(aq1, bk1, s, 0, 0, 0);
            sc[j] = s;
        }

        // scale + causal mask (C-layout: col = l16 + 16j, row = quad*4 + r)
        float rowmax[4];
#pragma unroll
        for (int r = 0; r < 4; r++) rowmax[r] = -1e30f;
#pragma unroll
        for (int j = 0; j < 4; j++) {
            int kk = kb + j * 16 + l16;
#pragma unroll
            for (int r = 0; r < 4; r++) {
                int qq = q0 + wave * 16 + quad * 4 + r;
                float sv = sc[j][r] * 0.125f;
                sv = (kk <= qq) ? sv : -1e30f;
                sc[j][r] = sv;
                rowmax[r] = fmaxf(rowmax[r], sv);
            }
        }
#pragma unroll
        for (int off = 8; off >= 1; off >>= 1)
#pragma unroll
            for (int r = 0; r < 4; r++)
                rowmax[r] = fmaxf(rowmax[r], __shfl_xor(rowmax[r], off));

        float alpha[4], rs[4];
#pragma unroll
        for (int r = 0; r < 4; r++) {
            float mn = fmaxf(m_r[r], rowmax[r]);
            alpha[r] = __expf(m_r[r] - mn);
            m_r[r] = mn;
        }
#pragma unroll
        for (int j = 0; j < 4; j++)
#pragma unroll
            for (int r = 0; r < 4; r++)
                sc[j][r] = __expf(sc[j][r] - m_r[r]);
#pragma unroll
        for (int r = 0; r < 4; r++)
            rs[r] = sc[0][r] + sc[1][r] + sc[2][r] + sc[3][r];
#pragma unroll
        for (int off = 8; off >= 1; off >>= 1)
#pragma unroll
            for (int r = 0; r < 4; r++) rs[r] += __shfl_xor(rs[r], off);
#pragma unroll
        for (int r = 0; r < 4; r++) l_r[r] = l_r[r] * alpha[r] + rs[r];
#pragma unroll
        for (int j = 0; j < 4; j++)
#pragma unroll
            for (int r = 0; r < 4; r++) O[j][r] *= alpha[r];

        // P: C-layout -> LDS -> A-layout
#pragma unroll
        for (int j = 0; j < 4; j++)
#pragma unroll
            for (int r = 0; r < 4; r++)
                Ps[wave][quad * 4 + r][j * 16 + l16] = f2b(sc[j][r]);
        __syncthreads();  // conservative (wave-private; remove once verified)

        bf16x8 ap0 = *reinterpret_cast<const bf16x8*>(&Ps[wave][l16][quad * 8]);
        bf16x8 ap1 = *reinterpret_cast<const bf16x8*>(&Ps[wave][l16][32 + quad * 8]);
#pragma unroll
        for (int j = 0; j < 4; j++) {
            bf16x8 bv0 = *reinterpret_cast<const bf16x8*>(&Vts[j * 16 + l16][quad * 8]);
            bf16x8 bv1 = *reinterpret_cast<const bf16x8*>(&Vts[j * 16 + l16][32 + quad * 8]);
            O[j] = __builtin_amdgcn_mfma_f32_16x16x32_bf16(ap0, bv0, O[j], 0, 0, 0);
            O[j] = __builtin_amdgcn_mfma_f32_16x16x32_bf16(ap1, bv1, O[j], 0, 0, 0);
        }
    }

    // epilogue: O/l -> Ob [B,S,C] bf16
    float inv[4];
#pragma unroll
    for (int r = 0; r < 4; r++) inv[r] = 1.f / l_r[r];
#pragma unroll
    for (int j = 0; j < 4; j++)
#pragma unroll
        for (int r = 0; r < 4; r++) {
            int s = q0 + wave * 16 + quad * 4 + r;
            Ob[((size_t)(b * SDIM + s)) * CDIM + h * 64 + j * 16 + l16] = f2b(O[j][r] * inv[r]);
        }
}

// ---------------------------------------------------------------------------
// K3: output projection. Ob bf16 [8192,1024] @ w_proj fp32 [1024,1024] + b.
// ---------------------------------------------------------------------------
__global__ __launch_bounds__(256) void proj_gemm(
    const unsigned short* __restrict__ A, const float* __restrict__ W,
    const float* __restrict__ bias, float* __restrict__ out)
{
    __shared__ __align__(16) unsigned short As[128][40];
    __shared__ __align__(16) unsigned short Bs[128][40];
    const int tid = threadIdx.x;
    const int lane = tid & 63;
    const int wave = tid >> 6;
    const int wm = wave >> 1, wn = wave & 1;
    const int l16 = lane & 15, quad = lane >> 4;
    const int m0 = blockIdx.y * 128;
    const int n0 = blockIdx.x * 128;
    const int N = CDIM, K = CDIM;

    f32x4 acc[4][4];
#pragma unroll
    for (int i = 0; i < 4; i++)
#pragma unroll
        for (int j = 0; j < 4; j++) acc[i][j] = (f32x4){0.f, 0.f, 0.f, 0.f};

    for (int k0 = 0; k0 < K; k0 += 32) {
        __syncthreads();
        // stage A (already bf16): 128x32 = 512 16B chunks
#pragma unroll
        for (int it = 0; it < 2; it++) {
            int c = tid + it * 256;
            int row = c >> 2, col = (c & 3) * 8;
            *reinterpret_cast<uint4*>(&As[row][col]) =
                *reinterpret_cast<const uint4*>(&A[(size_t)(m0 + row) * K + k0 + col]);
        }
        // stage B transposed
#pragma unroll
        for (int it = 0; it < 4; it++) {
            int c = tid + it * 256;
            int krow = c >> 5, nc = (c & 31) * 4;
            float4 f = *reinterpret_cast<const float4*>(&W[(size_t)(k0 + krow) * N + n0 + nc]);
            Bs[nc + 0][krow] = f2b(f.x);
            Bs[nc + 1][krow] = f2b(f.y);
            Bs[nc + 2][krow] = f2b(f.z);
            Bs[nc + 3][krow] = f2b(f.w);
        }
        __syncthreads();

        bf16x8 a[4], b[4];
#pragma unroll
        for (int i = 0; i < 4; i++)
            a[i] = *reinterpret_cast<const bf16x8*>(&As[wm * 64 + i * 16 + l16][quad * 8]);
#pragma unroll
        for (int j = 0; j < 4; j++)
            b[j] = *reinterpret_cast<const bf16x8*>(&Bs[wn * 64 + j * 16 + l16][quad * 8]);
#pragma unroll
        for (int i = 0; i < 4; i++)
#pragma unroll
            for (int j = 0; j < 4; j++)
                acc[i][j] = __builtin_amdgcn_mfma_f32_16x16x32_bf16(a[i], b[j], acc[i][j], 0, 0, 0);
    }

#pragma unroll
    for (int i = 0; i < 4; i++) {
        int mbase = m0 + wm * 64 + i * 16 + quad * 4;
#pragma unroll
        for (int j = 0; j < 4; j++) {
            int n = n0 + wn * 64 + j * 16 + l16;
            float bv = bias[n];
#pragma unroll
            for (int r = 0; r < 4; r++)
                out[(size_t)(mbase + r) * N + n] = acc[i][j][r] + bv;
        }
    }
}

extern "C" void kernel_launch(void* const* d_in, const int* in_sizes, int n_in,
                              void* d_out, int out_size, void* d_ws, size_t ws_size,
                              hipStream_t stream) {
    const float* x      = (const float*)d_in[0];
    const float* w_qkv  = (const float*)d_in[1];
    const float* b_qkv  = (const float*)d_in[2];
    const float* w_proj = (const float*)d_in[3];
    const float* b_proj = (const float*)d_in[4];
    float* out = (float*)d_out;

    const size_t per = (size_t)BDIM * HDIM * SDIM * DDIM;  // 8388608 elems
    unsigned short* Qb = (unsigned short*)d_ws;
    unsigned short* Kb = Qb + per;
    unsigned short* Vb = Kb + per;
    unsigned short* Ob = Vb + per;

    dim3 blk(256);
    qkv_gemm<<<dim3(3 * CDIM / 128, BDIM * SDIM / 128), blk, 0, stream>>>(
        x, w_qkv, b_qkv, Qb, Kb, Vb);
    attn<<<dim3(BDIM * HDIM * (SDIM / 64)), blk, 0, stream>>>(Qb, Kb, Vb, Ob);
    proj_gemm<<<dim3(CDIM / 128, BDIM * SDIM / 128), blk, 0, stream>>>(
        Ob, w_proj, b_proj, out);
}

// Round 3
// 421.901 us; speedup vs baseline: 1.7957x; 1.7957x over previous
//
#include <hip/hip_runtime.h>

#define SDIM 2048
#define CDIM 1024
#define BDIM 4
#define HDIM 16
#define DDIM 64

typedef __attribute__((ext_vector_type(8))) short bf16x8;
typedef __attribute__((ext_vector_type(4))) float f32x4;
typedef unsigned short u16;

__device__ __forceinline__ u16 f2b(float f) {
    union { float f; unsigned u; } v; v.f = f;
    unsigned r = v.u + 0x7FFFu + ((v.u >> 16) & 1u);
    return (u16)(r >> 16);
}

typedef const __attribute__((address_space(1))) unsigned int* gas_t;
typedef __attribute__((address_space(3))) unsigned int* las_t;
__device__ __forceinline__ void cp16(const void* g, void* l) {
    // 16B direct global->LDS; LDS dest = wave-uniform base + lane*16
    __builtin_amdgcn_global_load_lds((gas_t)g, (las_t)l, 16, 0, 0);
}

// ---------------------------------------------------------------------------
// conv_cast: fp32 -> bf16 elementwise (x). 8 elems/thread.
// ---------------------------------------------------------------------------
__global__ __launch_bounds__(256) void conv_cast(
    const float* __restrict__ src, u16* __restrict__ dst)
{
    int i = (blockIdx.x * 256 + threadIdx.x) * 8;
    float4 a = *reinterpret_cast<const float4*>(&src[i]);
    float4 b = *reinterpret_cast<const float4*>(&src[i + 4]);
    u16 u[8];
    u[0]=f2b(a.x); u[1]=f2b(a.y); u[2]=f2b(a.z); u[3]=f2b(a.w);
    u[4]=f2b(b.x); u[5]=f2b(b.y); u[6]=f2b(b.z); u[7]=f2b(b.w);
    *reinterpret_cast<uint4*>(&dst[i]) = *reinterpret_cast<uint4*>(u);
}

// ---------------------------------------------------------------------------
// conv_t: fp32 [K][N] -> bf16 [N][K] (weight transpose-convert), 64x64 tiles.
// ---------------------------------------------------------------------------
__global__ __launch_bounds__(256) void conv_t(
    const float* __restrict__ src, u16* __restrict__ dst, int K, int N)
{
    __shared__ __align__(16) u16 t[64][72];
    const int tid = threadIdx.x;
    const int k0 = blockIdx.y * 64, n0 = blockIdx.x * 64;
#pragma unroll
    for (int it = 0; it < 4; it++) {
        int c = tid + it * 256;            // 0..1023
        int r = c >> 4, c4 = (c & 15) * 4; // k-row, n-col group
        float4 f = *reinterpret_cast<const float4*>(&src[(size_t)(k0 + r) * N + n0 + c4]);
        t[c4 + 0][r] = f2b(f.x);
        t[c4 + 1][r] = f2b(f.y);
        t[c4 + 2][r] = f2b(f.z);
        t[c4 + 3][r] = f2b(f.w);
    }
    __syncthreads();
#pragma unroll
    for (int it = 0; it < 2; it++) {
        int c = tid + it * 256;            // 0..511
        int r = c >> 3, c8 = (c & 7) * 8;  // n-row, k chunk
        *reinterpret_cast<uint4*>(&dst[(size_t)(n0 + r) * K + k0 + c8]) =
            *reinterpret_cast<const uint4*>(&t[r][c8]);
    }
}

// ---------------------------------------------------------------------------
// gemm_qkv: Xb bf16 [8192][1024] @ WqT bf16 [3072][1024]^T + b ->
//   Q,K [B,H,S,D] bf16 ; V transposed [B,H,D,S] bf16.
// m97 structure: 128x128x32 tiles, global_load_lds width=16.
// ---------------------------------------------------------------------------
__global__ __launch_bounds__(256) void gemm_qkv(
    const u16* __restrict__ A, const u16* __restrict__ Bt,
    const float* __restrict__ bias,
    u16* __restrict__ Qb, u16* __restrict__ Kb, u16* __restrict__ Vtb)
{
    __shared__ __align__(16) u16 As[128 * 32];
    __shared__ __align__(16) u16 Bs[128 * 32];
    const int tid = threadIdx.x, lane = tid & 63, wave = tid >> 6;
    const int wm = wave >> 1, wn = wave & 1;
    const int l16 = lane & 15, quad = lane >> 4;
    const int m0 = blockIdx.y * 128, n0 = blockIdx.x * 128;
    const int K = CDIM;

    // staging chunk coords: chunk cl = wave*128 + call*64 + lane; row=cl>>2 ch=cl&3
    const int cl0 = wave * 128 + lane;
    const int r0 = cl0 >> 2, c0 = cl0 & 3;
    const int r1 = r0 + 16;  // call 1: +64 chunks = +16 rows, same ch

    f32x4 acc[4][4];
#pragma unroll
    for (int i = 0; i < 4; i++)
#pragma unroll
        for (int j = 0; j < 4; j++) acc[i][j] = (f32x4){0.f, 0.f, 0.f, 0.f};

    for (int k0 = 0; k0 < K; k0 += 32) {
        __syncthreads();
        cp16(&A [(size_t)(m0 + r0) * K + k0 + c0 * 8], &As[wave * 1024]);
        cp16(&A [(size_t)(m0 + r1) * K + k0 + c0 * 8], &As[wave * 1024 + 512]);
        cp16(&Bt[(size_t)(n0 + r0) * K + k0 + c0 * 8], &Bs[wave * 1024]);
        cp16(&Bt[(size_t)(n0 + r1) * K + k0 + c0 * 8], &Bs[wave * 1024 + 512]);
        __syncthreads();

        bf16x8 a[4], b[4];
#pragma unroll
        for (int i = 0; i < 4; i++)
            a[i] = *reinterpret_cast<const bf16x8*>(&As[((wm * 64 + i * 16 + l16) * 4 + quad) * 8]);
#pragma unroll
        for (int j = 0; j < 4; j++)
            b[j] = *reinterpret_cast<const bf16x8*>(&Bs[((wn * 64 + j * 16 + l16) * 4 + quad) * 8]);
#pragma unroll
        for (int i = 0; i < 4; i++)
#pragma unroll
            for (int j = 0; j < 4; j++)
                acc[i][j] = __builtin_amdgcn_mfma_f32_16x16x32_bf16(a[i], b[j], acc[i][j], 0, 0, 0);
    }

#pragma unroll
    for (int i = 0; i < 4; i++) {
        int mbase = m0 + wm * 64 + i * 16 + quad * 4;
#pragma unroll
        for (int j = 0; j < 4; j++) {
            int n = n0 + wn * 64 + j * 16 + l16;
            float bv = bias[n];
            int which = n >> 10;
            int cc = n & 1023;
            int h = cc >> 6, d = cc & 63;
#pragma unroll
            for (int r = 0; r < 4; r++) {
                int mm = mbase + r;
                int bb = mm >> 11, s = mm & 2047;
                u16 val = f2b(acc[i][j][r] + bv);
                if (which == 2) {
                    Vtb[((size_t)((bb * HDIM + h) * DDIM + d)) * SDIM + s] = val;
                } else {
                    u16* dst = (which == 0) ? Qb : Kb;
                    dst[((size_t)((bb * HDIM + h) * SDIM + s)) * DDIM + d] = val;
                }
            }
        }
    }
}

// ---------------------------------------------------------------------------
// attn: causal flash attention. Block = (b,h, 64 q-rows), 4 waves x 16 q-rows.
// K tile [64][64] and Vt tile [64 d][64 keys] staged via global_load_lds with
// XOR-8 chunk swizzle (slot = row*8 + (chunk ^ (row&7))) for conflict-free
// b128 fragment reads at 128B pitch.
// ---------------------------------------------------------------------------
__global__ __launch_bounds__(256) void attn(
    const u16* __restrict__ Qb, const u16* __restrict__ Kb,
    const u16* __restrict__ Vtb, u16* __restrict__ Ob)
{
    __shared__ __align__(16) u16 Qs[64 * 64];
    __shared__ __align__(16) u16 Ks[64 * 64];
    __shared__ __align__(16) u16 Vts[64 * 64];
    __shared__ __align__(16) u16 Ps[4][16 * 72];

    const int tid = threadIdx.x;
    const int lane = tid & 63, wave = tid >> 6;
    const int l16 = lane & 15, quad = lane >> 4;
    const int bh = blockIdx.x >> 5;
    const int qt = 31 - (blockIdx.x & 31);   // longest q-tiles dispatch first
    const int q0 = qt * 64;
    const int b = bh >> 4, h = bh & 15;
    const size_t base = (size_t)bh * SDIM * DDIM;  // same count for QK and Vt

    // staging coords: chunk cl = wave*128 + call*64 + lane
    const int cl0 = wave * 128 + lane;
    const int sr0 = cl0 >> 3, sc0 = cl0 & 7;
    const int sg0 = sc0 ^ (sr0 & 7);     // +8 rows doesn't change row&7
    const int sr1 = sr0 + 8;

    // stage Q tile (swizzled)
    cp16(&Qb[base + (size_t)(q0 + sr0) * DDIM + sg0 * 8], &Qs[wave * 1024]);
    cp16(&Qb[base + (size_t)(q0 + sr1) * DDIM + sg0 * 8], &Qs[wave * 1024 + 512]);
    __syncthreads();

    const int qr = wave * 16 + l16;
    const bf16x8 aq0 = *reinterpret_cast<const bf16x8*>(&Qs[(qr * 8 + ( quad      ^ (qr & 7))) * 8]);
    const bf16x8 aq1 = *reinterpret_cast<const bf16x8*>(&Qs[(qr * 8 + ((quad + 4) ^ (qr & 7))) * 8]);

    f32x4 O[4];
#pragma unroll
    for (int j = 0; j < 4; j++) O[j] = (f32x4){0.f, 0.f, 0.f, 0.f};
    float m_r[4], l_r[4];
#pragma unroll
    for (int r = 0; r < 4; r++) { m_r[r] = -1e30f; l_r[r] = 0.f; }

    for (int kbi = 0; kbi <= qt; kbi++) {
        const int kb = kbi * 64;
        const bool diag = (kbi == qt);
        // stage K rows + Vt rows (Vt global layout [B,H,D,S]: row=d, contiguous in s)
        cp16(&Kb [base + (size_t)(kb + sr0) * DDIM + sg0 * 8], &Ks[wave * 1024]);
        cp16(&Kb [base + (size_t)(kb + sr1) * DDIM + sg0 * 8], &Ks[wave * 1024 + 512]);
        cp16(&Vtb[base + (size_t)sr0 * SDIM + kb + sg0 * 8], &Vts[wave * 1024]);
        cp16(&Vtb[base + (size_t)sr1 * SDIM + kb + sg0 * 8], &Vts[wave * 1024 + 512]);
        __syncthreads();

        // QK^T: 16 q-rows x 64 keys per wave
        f32x4 sc[4];
#pragma unroll
        for (int j = 0; j < 4; j++) {
            int kr = j * 16 + l16;
            bf16x8 bk0 = *reinterpret_cast<const bf16x8*>(&Ks[(kr * 8 + ( quad      ^ (kr & 7))) * 8]);
            bf16x8 bk1 = *reinterpret_cast<const bf16x8*>(&Ks[(kr * 8 + ((quad + 4) ^ (kr & 7))) * 8]);
            f32x4 s = (f32x4){0.f, 0.f, 0.f, 0.f};
            s = __builtin_amdgcn_mfma_f32_16x16x32_bf16(aq0, bk0, s, 0, 0, 0);
            s = __builtin_amdgcn_mfma_f32_16x16x32_bf16(aq1, bk1, s, 0, 0, 0);
            sc[j] = s;
        }

        // scale + (diagonal-only) causal mask; C-layout: col=l16+16j, row=quad*4+r
        // tile-local q row = wave*16 + quad*4 + r  (R2 bug: missing wave*16)
        float rowmax[4];
#pragma unroll
        for (int r = 0; r < 4; r++) rowmax[r] = -1e30f;
#pragma unroll
        for (int j = 0; j < 4; j++) {
            int kk = j * 16 + l16;
#pragma unroll
            for (int r = 0; r < 4; r++) {
                float sv = sc[j][r] * 0.125f;
                if (diag) {
                    int qq = wave * 16 + quad * 4 + r;
                    sv = (kk <= qq) ? sv : -1e30f;
                }
                sc[j][r] = sv;
                rowmax[r] = fmaxf(rowmax[r], sv);
            }
        }
#pragma unroll
        for (int off = 8; off >= 1; off >>= 1)
#pragma unroll
            for (int r = 0; r < 4; r++)
                rowmax[r] = fmaxf(rowmax[r], __shfl_xor(rowmax[r], off));

        float alpha[4], rs[4];
#pragma unroll
        for (int r = 0; r < 4; r++) {
            float mn = fmaxf(m_r[r], rowmax[r]);
            alpha[r] = __expf(m_r[r] - mn);
            m_r[r] = mn;
        }
#pragma unroll
        for (int j = 0; j < 4; j++)
#pragma unroll
            for (int r = 0; r < 4; r++)
                sc[j][r] = __expf(sc[j][r] - m_r[r]);
#pragma unroll
        for (int r = 0; r < 4; r++)
            rs[r] = sc[0][r] + sc[1][r] + sc[2][r] + sc[3][r];
#pragma unroll
        for (int off = 8; off >= 1; off >>= 1)
#pragma unroll
            for (int r = 0; r < 4; r++) rs[r] += __shfl_xor(rs[r], off);
#pragma unroll
        for (int r = 0; r < 4; r++) l_r[r] = l_r[r] * alpha[r] + rs[r];
#pragma unroll
        for (int j = 0; j < 4; j++)
#pragma unroll
            for (int r = 0; r < 4; r++) O[j][r] *= alpha[r];

        // P: C-layout -> LDS (wave-private; same-wave DS ops are in order) -> A-layout
#pragma unroll
        for (int j = 0; j < 4; j++)
#pragma unroll
            for (int r = 0; r < 4; r++)
                Ps[wave][(quad * 4 + r) * 72 + j * 16 + l16] = f2b(sc[j][r]);

        bf16x8 ap0 = *reinterpret_cast<const bf16x8*>(&Ps[wave][l16 * 72 + quad * 8]);
        bf16x8 ap1 = *reinterpret_cast<const bf16x8*>(&Ps[wave][l16 * 72 + 32 + quad * 8]);
#pragma unroll
        for (int j = 0; j < 4; j++) {
            int vr = j * 16 + l16;  // d index
            bf16x8 bv0 = *reinterpret_cast<const bf16x8*>(&Vts[(vr * 8 + ( quad      ^ (vr & 7))) * 8]);
            bf16x8 bv1 = *reinterpret_cast<const bf16x8*>(&Vts[(vr * 8 + ((quad + 4) ^ (vr & 7))) * 8]);
            O[j] = __builtin_amdgcn_mfma_f32_16x16x32_bf16(ap0, bv0, O[j], 0, 0, 0);
            O[j] = __builtin_amdgcn_mfma_f32_16x16x32_bf16(ap1, bv1, O[j], 0, 0, 0);
        }
        __syncthreads();
    }

    // epilogue: O/l -> Ob [B,S,C] bf16
    float inv[4];
#pragma unroll
    for (int r = 0; r < 4; r++) inv[r] = 1.f / l_r[r];
#pragma unroll
    for (int j = 0; j < 4; j++)
#pragma unroll
        for (int r = 0; r < 4; r++) {
            int s = q0 + wave * 16 + quad * 4 + r;
            Ob[((size_t)(b * SDIM + s)) * CDIM + h * 64 + j * 16 + l16] = f2b(O[j][r] * inv[r]);
        }
}

// ---------------------------------------------------------------------------
// gemm_proj: Ob bf16 [8192][1024] @ WpT bf16 [1024][1024]^T + b -> fp32 out.
// ---------------------------------------------------------------------------
__global__ __launch_bounds__(256) void gemm_proj(
    const u16* __restrict__ A, const u16* __restrict__ Bt,
    const float* __restrict__ bias, float* __restrict__ out)
{
    __shared__ __align__(16) u16 As[128 * 32];
    __shared__ __align__(16) u16 Bs[128 * 32];
    const int tid = threadIdx.x, lane = tid & 63, wave = tid >> 6;
    const int wm = wave >> 1, wn = wave & 1;
    const int l16 = lane & 15, quad = lane >> 4;
    const int m0 = blockIdx.y * 128, n0 = blockIdx.x * 128;
    const int K = CDIM, N = CDIM;

    const int cl0 = wave * 128 + lane;
    const int r0 = cl0 >> 2, c0 = cl0 & 3;
    const int r1 = r0 + 16;

    f32x4 acc[4][4];
#pragma unroll
    for (int i = 0; i < 4; i++)
#pragma unroll
        for (int j = 0; j < 4; j++) acc[i][j] = (f32x4){0.f, 0.f, 0.f, 0.f};

    for (int k0 = 0; k0 < K; k0 += 32) {
        __syncthreads();
        cp16(&A [(size_t)(m0 + r0) * K + k0 + c0 * 8], &As[wave * 1024]);
        cp16(&A [(size_t)(m0 + r1) * K + k0 + c0 * 8], &As[wave * 1024 + 512]);
        cp16(&Bt[(size_t)(n0 + r0) * K + k0 + c0 * 8], &Bs[wave * 1024]);
        cp16(&Bt[(size_t)(n0 + r1) * K + k0 + c0 * 8], &Bs[wave * 1024 + 512]);
        __syncthreads();

        bf16x8 a[4], b[4];
#pragma unroll
        for (int i = 0; i < 4; i++)
            a[i] = *reinterpret_cast<const bf16x8*>(&As[((wm * 64 + i * 16 + l16) * 4 + quad) * 8]);
#pragma unroll
        for (int j = 0; j < 4; j++)
            b[j] = *reinterpret_cast<const bf16x8*>(&Bs[((wn * 64 + j * 16 + l16) * 4 + quad) * 8]);
#pragma unroll
        for (int i = 0; i < 4; i++)
#pragma unroll
            for (int j = 0; j < 4; j++)
                acc[i][j] = __builtin_amdgcn_mfma_f32_16x16x32_bf16(a[i], b[j], acc[i][j], 0, 0, 0);
    }

#pragma unroll
    for (int i = 0; i < 4; i++) {
        int mbase = m0 + wm * 64 + i * 16 + quad * 4;
#pragma unroll
        for (int j = 0; j < 4; j++) {
            int n = n0 + wn * 64 + j * 16 + l16;
            float bv = bias[n];
#pragma unroll
            for (int r = 0; r < 4; r++)
                out[(size_t)(mbase + r) * N + n] = acc[i][j][r] + bv;
        }
    }
}

extern "C" void kernel_launch(void* const* d_in, const int* in_sizes, int n_in,
                              void* d_out, int out_size, void* d_ws, size_t ws_size,
                              hipStream_t stream) {
    const float* x      = (const float*)d_in[0];
    const float* w_qkv  = (const float*)d_in[1];
    const float* b_qkv  = (const float*)d_in[2];
    const float* w_proj = (const float*)d_in[3];
    const float* b_proj = (const float*)d_in[4];
    float* out = (float*)d_out;

    const size_t per = (size_t)BDIM * HDIM * SDIM * DDIM;  // 8388608
    u16* Qb  = (u16*)d_ws;
    u16* Kb  = Qb + per;
    u16* Vtb = Kb + per;
    u16* Ob  = Vtb + per;
    u16* Xb  = Ob;            // alias: Xb dead before attn writes Ob
    u16* WqT = Ob + per;
    u16* WpT = WqT + (size_t)3 * CDIM * CDIM;

    dim3 blk(256);
    conv_cast<<<dim3(per / (256 * 8)), blk, 0, stream>>>(x, Xb);
    conv_t<<<dim3(3 * CDIM / 64, CDIM / 64), blk, 0, stream>>>(w_qkv, WqT, CDIM, 3 * CDIM);
    conv_t<<<dim3(CDIM / 64, CDIM / 64), blk, 0, stream>>>(w_proj, WpT, CDIM, CDIM);

    gemm_qkv<<<dim3(3 * CDIM / 128, BDIM * SDIM / 128), blk, 0, stream>>>(
        Xb, WqT, b_qkv, Qb, Kb, Vtb);
    attn<<<dim3(BDIM * HDIM * (SDIM / 64)), blk, 0, stream>>>(Qb, Kb, Vtb, Ob);
    gemm_proj<<<dim3(CDIM / 128, BDIM * SDIM / 128), blk, 0, stream>>>(
        Ob, WpT, b_proj, out);
}

// Round 5
// 312.747 us; speedup vs baseline: 2.4224x; 1.3490x over previous
//
#include <hip/hip_runtime.h>

#define SDIM 2048
#define CDIM 1024
#define BDIM 4
#define HDIM 16
#define DDIM 64

// 0.125 (1/sqrt(D)) * log2(e), folded into Q so P = exp2(q.k_scaled)
#define ATT_SCALE 0.18033688011112042f

typedef __attribute__((ext_vector_type(8))) short bf16x8;
typedef __attribute__((ext_vector_type(4))) short bf16x4;
typedef __attribute__((ext_vector_type(4))) float f32x4;
typedef unsigned short u16;

#define MFMA __builtin_amdgcn_mfma_f32_16x16x32_bf16
// Compiler-only fence: pins program order of type-punned LDS store->load pairs
// (TBAA would otherwise allow hoisting the loads above the stores). Same-wave
// DS ops execute in order in HW, so no s_waitcnt semantics are needed.
#define LDS_ORDER_FENCE() __asm__ __volatile__("" ::: "memory")

__device__ __forceinline__ u16 f2b(float f) {   // RTNE
    union { float f; unsigned u; } v; v.f = f;
    unsigned r = v.u + 0x7FFFu + ((v.u >> 16) & 1u);
    return (u16)(r >> 16);
}
__device__ __forceinline__ u16 f2b_trunc(float f) {  // cheap, for P only
    union { float f; unsigned u; } v; v.f = f;
    return (u16)(v.u >> 16);
}

typedef const __attribute__((address_space(1))) unsigned int* gas_t;
typedef __attribute__((address_space(3))) unsigned int* las_t;
__device__ __forceinline__ void cp16(const void* g, void* l) {
    // 16B direct global->LDS; LDS dest = wave-uniform base + lane*16
    __builtin_amdgcn_global_load_lds((gas_t)g, (las_t)l, 16, 0, 0);
}

__device__ __forceinline__ float fast_exp2(float x) {
#if __has_builtin(__builtin_amdgcn_exp2f)
    return __builtin_amdgcn_exp2f(x);
#else
    return __exp2f(x);
#endif
}

// ---------------------------------------------------------------------------
// conv_cast: fp32 -> bf16 elementwise (x). 8 elems/thread.
// ---------------------------------------------------------------------------
__global__ __launch_bounds__(256) void conv_cast(
    const float* __restrict__ src, u16* __restrict__ dst)
{
    int i = (blockIdx.x * 256 + threadIdx.x) * 8;
    float4 a = *reinterpret_cast<const float4*>(&src[i]);
    float4 b = *reinterpret_cast<const float4*>(&src[i + 4]);
    u16 u[8];
    u[0]=f2b(a.x); u[1]=f2b(a.y); u[2]=f2b(a.z); u[3]=f2b(a.w);
    u[4]=f2b(b.x); u[5]=f2b(b.y); u[6]=f2b(b.z); u[7]=f2b(b.w);
    *reinterpret_cast<uint4*>(&dst[i]) = *reinterpret_cast<uint4*>(u);
}

// ---------------------------------------------------------------------------
// conv_t: fp32 [K][N] -> bf16 [N][K] (weight transpose-convert), 64x64 tiles.
// ---------------------------------------------------------------------------
__global__ __launch_bounds__(256) void conv_t(
    const float* __restrict__ src, u16* __restrict__ dst, int K, int N)
{
    __shared__ __align__(16) u16 t[64][72];
    const int tid = threadIdx.x;
    const int k0 = blockIdx.y * 64, n0 = blockIdx.x * 64;
#pragma unroll
    for (int it = 0; it < 4; it++) {
        int c = tid + it * 256;
        int r = c >> 4, c4 = (c & 15) * 4;
        float4 f = *reinterpret_cast<const float4*>(&src[(size_t)(k0 + r) * N + n0 + c4]);
        t[c4 + 0][r] = f2b(f.x);
        t[c4 + 1][r] = f2b(f.y);
        t[c4 + 2][r] = f2b(f.z);
        t[c4 + 3][r] = f2b(f.w);
    }
    __syncthreads();
#pragma unroll
    for (int it = 0; it < 2; it++) {
        int c = tid + it * 256;
        int r = c >> 3, c8 = (c & 7) * 8;
        *reinterpret_cast<uint4*>(&dst[(size_t)(n0 + r) * K + k0 + c8]) =
            *reinterpret_cast<const uint4*>(&t[r][c8]);
    }
}

// ---------------------------------------------------------------------------
// gemm_qkv: Xb bf16 [8192][1024] @ WqT bf16 [3072][1024]^T + b ->
//   Q (pre-scaled by ATT_SCALE), K in [B,H,S,D]; V transposed [B,H,D,S].
// V epilogue goes through an LDS transpose for coalesced global writes.
// ---------------------------------------------------------------------------
__global__ __launch_bounds__(256) void gemm_qkv(
    const u16* __restrict__ A, const u16* __restrict__ Bt,
    const float* __restrict__ bias,
    u16* __restrict__ Qb, u16* __restrict__ Kb, u16* __restrict__ Vtb)
{
    __shared__ __align__(16) u16 As[128 * 32];
    __shared__ __align__(16) u16 Bs[128 * 32];
    __shared__ __align__(16) u16 Vt[4][64 * 72];
    const int tid = threadIdx.x, lane = tid & 63, wave = tid >> 6;
    const int wm = wave >> 1, wn = wave & 1;
    const int l16 = lane & 15, quad = lane >> 4;
    const int m0 = blockIdx.y * 128, n0 = blockIdx.x * 128;
    const int K = CDIM;

    const int cl0 = wave * 128 + lane;
    const int r0 = cl0 >> 2, c0 = cl0 & 3;
    const int r1 = r0 + 16;

    f32x4 acc[4][4];
#pragma unroll
    for (int i = 0; i < 4; i++)
#pragma unroll
        for (int j = 0; j < 4; j++) acc[i][j] = (f32x4){0.f, 0.f, 0.f, 0.f};

    for (int k0 = 0; k0 < K; k0 += 32) {
        __syncthreads();
        cp16(&A [(size_t)(m0 + r0) * K + k0 + c0 * 8], &As[wave * 1024]);
        cp16(&A [(size_t)(m0 + r1) * K + k0 + c0 * 8], &As[wave * 1024 + 512]);
        cp16(&Bt[(size_t)(n0 + r0) * K + k0 + c0 * 8], &Bs[wave * 1024]);
        cp16(&Bt[(size_t)(n0 + r1) * K + k0 + c0 * 8], &Bs[wave * 1024 + 512]);
        __syncthreads();

        bf16x8 a[4], b[4];
#pragma unroll
        for (int i = 0; i < 4; i++)
            a[i] = *reinterpret_cast<const bf16x8*>(&As[((wm * 64 + i * 16 + l16) * 4 + quad) * 8]);
#pragma unroll
        for (int j = 0; j < 4; j++)
            b[j] = *reinterpret_cast<const bf16x8*>(&Bs[((wn * 64 + j * 16 + l16) * 4 + quad) * 8]);
#pragma unroll
        for (int i = 0; i < 4; i++)
#pragma unroll
            for (int j = 0; j < 4; j++)
                acc[i][j] = MFMA(a[i], b[j], acc[i][j], 0, 0, 0);
    }

    const int mm0 = m0 + wm * 64;
    const int bidx = mm0 >> 11, s0 = mm0 & 2047;

    if (n0 >= 2 * CDIM) {
        // ---- V block: LDS transpose -> coalesced [B,H,D,S] writes ----
        const int h = (n0 + wn * 64 - 2 * CDIM) >> 6;  // d0 = 0 (64-aligned)
#pragma unroll
        for (int j = 0; j < 4; j++) {
            float bv = bias[n0 + wn * 64 + j * 16 + l16];
#pragma unroll
            for (int i = 0; i < 4; i++)
#pragma unroll
                for (int r = 0; r < 4; r++)
                    Vt[wave][(j * 16 + l16) * 72 + i * 16 + quad * 4 + r] =
                        f2b(acc[i][j][r] + bv);
        }
        LDS_ORDER_FENCE();   // u16 stores -> uint4 loads: pin order vs TBAA
        const size_t gb = ((size_t)(bidx * HDIM + h)) * DDIM * SDIM;
#pragma unroll
        for (int p = 0; p < 8; p++) {
            int rr = p * 8 + (lane >> 3), ch = lane & 7;
            uint4 v = *reinterpret_cast<const uint4*>(&Vt[wave][rr * 72 + ch * 8]);
            *reinterpret_cast<uint4*>(&Vtb[gb + (size_t)rr * SDIM + s0 + ch * 8]) = v;
        }
    } else {
        // ---- Q or K block (uniform per block) ----
        const bool isK = (n0 >= CDIM);
        u16* dst = isK ? Kb : Qb;
        const float scale = isK ? 1.0f : ATT_SCALE;
#pragma unroll
        for (int j = 0; j < 4; j++) {
            int n = n0 + wn * 64 + j * 16 + l16;
            float bv = bias[n];
            int cc = n & 1023;
            int hh = cc >> 6, d = cc & 63;
            const size_t hb = ((size_t)(bidx * HDIM + hh)) * SDIM;
#pragma unroll
            for (int i = 0; i < 4; i++)
#pragma unroll
                for (int r = 0; r < 4; r++) {
                    int s = s0 + i * 16 + quad * 4 + r;
                    dst[(hb + s) * DDIM + d] = f2b((acc[i][j][r] + bv) * scale);
                }
        }
    }
}

// ---------------------------------------------------------------------------
// attn: causal flash attention, no-max-shift softmax (safe: |scores|<~9,
// exp2 overflow needs 2^128), row-sums via ones-column MFMA.
// Block = (b,h, 128 q-rows), 4 waves x 32 rows (2 groups of 16).
// K/V double-buffered via global_load_lds, ONE barrier per k-block:
// prefetch issued right after barrier, drained at the next barrier.
// ---------------------------------------------------------------------------
__global__ __launch_bounds__(256, 3) void attn(
    const u16* __restrict__ Qb, const u16* __restrict__ Kb,
    const u16* __restrict__ Vtb, u16* __restrict__ Ob)
{
    __shared__ __align__(16) u16 Ks[2][64 * 64];
    __shared__ __align__(16) u16 Vts[2][64 * 64];
    __shared__ __align__(16) u16 Ps[4][32 * 68];   // pitch 136B: conflict-free P writes

    const int tid = threadIdx.x;
    const int lane = tid & 63, wave = tid >> 6;
    const int l16 = lane & 15, quad = lane >> 4;
    const int bh = blockIdx.x >> 4;
    const int qt = 15 - (blockIdx.x & 15);     // longest q-tiles first
    const int q0 = qt * 128;
    const int b = bh >> 4, h = bh & 15;
    const size_t base = (size_t)bh * (SDIM * DDIM);

    // staging chunk coords (8KB tile = 512 x 16B chunks, 2 cp16/wave/tile)
    const int cl0 = wave * 128 + lane;
    const int sr0 = cl0 >> 3, scc = cl0 & 7;
    const int sg0 = scc ^ (sr0 & 7);           // XOR-8 swizzle
    const int sr1 = sr0 + 8;

    // Q fragments straight from global (pre-scaled by ATT_SCALE in gemm_qkv)
    bf16x8 aq[2][2];
#pragma unroll
    for (int g = 0; g < 2; g++)
#pragma unroll
        for (int hh = 0; hh < 2; hh++)
            aq[g][hh] = *reinterpret_cast<const bf16x8*>(
                &Qb[base + (size_t)(q0 + wave * 32 + g * 16 + l16) * DDIM + hh * 32 + quad * 8]);

    u16* Pw = &Ps[wave][0];

    f32x4 O[2][4];
    f32x4 Osum[2];
#pragma unroll
    for (int g = 0; g < 2; g++) {
        Osum[g] = (f32x4){0.f, 0.f, 0.f, 0.f};
#pragma unroll
        for (int j = 0; j < 4; j++) O[g][j] = (f32x4){0.f, 0.f, 0.f, 0.f};
    }
    // ones-column B fragment: lanes with n==0 hold 1.0bf16 in all 8 slots
    const short onev = (l16 == 0) ? (short)0x3F80 : (short)0;
    const bf16x8 bones = {onev, onev, onev, onev, onev, onev, onev, onev};

    const int nkb = (qt + 1) * 2;

    // prefetch k-block 0 into buf 0
    {
        u16* kd = &Ks[0][wave * 1024];
        u16* vd = &Vts[0][wave * 1024];
        cp16(&Kb [base + (size_t)(sr0) * DDIM + sg0 * 8], kd);
        cp16(&Kb [base + (size_t)(sr1) * DDIM + sg0 * 8], kd + 512);
        cp16(&Vtb[base + (size_t)sr0 * SDIM + sg0 * 8], vd);
        cp16(&Vtb[base + (size_t)sr1 * SDIM + sg0 * 8], vd + 512);
    }

    for (int kbi = 0; kbi < nkb; kbi++) {
        const int cur = kbi & 1;
        const int kb = kbi * 64;
        __syncthreads();   // drains prev prefetch (vmcnt) + syncs buffer reuse
        if (kbi + 1 < nkb) {
            const int kb2 = kb + 64;
            u16* kd = &Ks[1 - cur][wave * 1024];
            u16* vd = &Vts[1 - cur][wave * 1024];
            cp16(&Kb [base + (size_t)(kb2 + sr0) * DDIM + sg0 * 8], kd);
            cp16(&Kb [base + (size_t)(kb2 + sr1) * DDIM + sg0 * 8], kd + 512);
            cp16(&Vtb[base + (size_t)sr0 * SDIM + kb2 + sg0 * 8], vd);
            cp16(&Vtb[base + (size_t)sr1 * SDIM + kb2 + sg0 * 8], vd + 512);
        }
        const u16* Kc = &Ks[cur][0];
        const u16* Vc = &Vts[cur][0];

#pragma unroll
        for (int g = 0; g < 2; g++) {
            const int Arow = q0 + wave * 32 + g * 16;   // group's first q-row
            if (kb > Arow + 15) continue;               // fully masked group

            // QK^T: 16 rows x 64 keys
            f32x4 sc[4];
#pragma unroll
            for (int j = 0; j < 4; j++) {
                int kr = j * 16 + l16;
                bf16x8 bk0 = *reinterpret_cast<const bf16x8*>(&Kc[(kr * 8 + ( quad      ^ (kr & 7))) * 8]);
                bf16x8 bk1 = *reinterpret_cast<const bf16x8*>(&Kc[(kr * 8 + ((quad + 4) ^ (kr & 7))) * 8]);
                f32x4 s = (f32x4){0.f, 0.f, 0.f, 0.f};
                s = MFMA(aq[g][0], bk0, s, 0, 0, 0);
                s = MFMA(aq[g][1], bk1, s, 0, 0, 0);
                sc[j] = s;
            }
            // causal mask (diagonal blocks only)
            if (kb + 63 > Arow) {
                const int qrel = Arow - kb;
#pragma unroll
                for (int j = 0; j < 4; j++) {
                    int kk = j * 16 + l16;
#pragma unroll
                    for (int r = 0; r < 4; r++)
                        sc[j][r] = (kk <= qrel + quad * 4 + r) ? sc[j][r] : -1e30f;
                }
            }
            // P = exp2(s), truncate to bf16, C-layout -> LDS
#pragma unroll
            for (int j = 0; j < 4; j++)
#pragma unroll
                for (int r = 0; r < 4; r++) {
                    float p = fast_exp2(sc[j][r]);
                    Pw[(g * 16 + quad * 4 + r) * 68 + j * 16 + l16] = f2b_trunc(p);
                }
            LDS_ORDER_FENCE();   // u16 stores -> vector loads: pin order vs TBAA
            // read back as A-fragments (bf16x4 pairs; pitch 136B = 8B-aligned)
            union { bf16x4 h[2]; bf16x8 f; } a0u, a1u;
            a0u.h[0] = *reinterpret_cast<const bf16x4*>(&Pw[(g * 16 + l16) * 68 + quad * 8]);
            a0u.h[1] = *reinterpret_cast<const bf16x4*>(&Pw[(g * 16 + l16) * 68 + quad * 8 + 4]);
            a1u.h[0] = *reinterpret_cast<const bf16x4*>(&Pw[(g * 16 + l16) * 68 + 32 + quad * 8]);
            a1u.h[1] = *reinterpret_cast<const bf16x4*>(&Pw[(g * 16 + l16) * 68 + 32 + quad * 8 + 4]);

            // PV + free row-sum via ones column
#pragma unroll
            for (int j = 0; j < 4; j++) {
                int vr = j * 16 + l16;
                bf16x8 bv0 = *reinterpret_cast<const bf16x8*>(&Vc[(vr * 8 + ( quad      ^ (vr & 7))) * 8]);
                bf16x8 bv1 = *reinterpret_cast<const bf16x8*>(&Vc[(vr * 8 + ((quad + 4) ^ (vr & 7))) * 8]);
                O[g][j] = MFMA(a0u.f, bv0, O[g][j], 0, 0, 0);
                O[g][j] = MFMA(a1u.f, bv1, O[g][j], 0, 0, 0);
            }
            Osum[g] = MFMA(a0u.f, bones, Osum[g], 0, 0, 0);
            Osum[g] = MFMA(a1u.f, bones, Osum[g], 0, 0, 0);
        }
    }

    // epilogue: normalize and store [B,S,C] bf16
#pragma unroll
    for (int g = 0; g < 2; g++)
#pragma unroll
        for (int r = 0; r < 4; r++) {
            float l = __shfl(Osum[g][r], (lane & 48));  // broadcast from l16==0 of quad
            float inv = 1.0f / l;
            int s = q0 + wave * 32 + g * 16 + quad * 4 + r;
#pragma unroll
            for (int j = 0; j < 4; j++)
                Ob[((size_t)(b * SDIM + s)) * CDIM + h * 64 + j * 16 + l16] =
                    f2b(O[g][j][r] * inv);
        }
}

// ---------------------------------------------------------------------------
// gemm_proj: Ob bf16 [8192][1024] @ WpT bf16 [1024][1024]^T + b -> fp32 out.
// ---------------------------------------------------------------------------
__global__ __launch_bounds__(256) void gemm_proj(
    const u16* __restrict__ A, const u16* __restrict__ Bt,
    const float* __restrict__ bias, float* __restrict__ out)
{
    __shared__ __align__(16) u16 As[128 * 32];
    __shared__ __align__(16) u16 Bs[128 * 32];
    const int tid = threadIdx.x, lane = tid & 63, wave = tid >> 6;
    const int wm = wave >> 1, wn = wave & 1;
    const int l16 = lane & 15, quad = lane >> 4;
    const int m0 = blockIdx.y * 128, n0 = blockIdx.x * 128;
    const int K = CDIM, N = CDIM;

    const int cl0 = wave * 128 + lane;
    const int r0 = cl0 >> 2, c0 = cl0 & 3;
    const int r1 = r0 + 16;

    f32x4 acc[4][4];
#pragma unroll
    for (int i = 0; i < 4; i++)
#pragma unroll
        for (int j = 0; j < 4; j++) acc[i][j] = (f32x4){0.f, 0.f, 0.f, 0.f};

    for (int k0 = 0; k0 < K; k0 += 32) {
        __syncthreads();
        cp16(&A [(size_t)(m0 + r0) * K + k0 + c0 * 8], &As[wave * 1024]);
        cp16(&A [(size_t)(m0 + r1) * K + k0 + c0 * 8], &As[wave * 1024 + 512]);
        cp16(&Bt[(size_t)(n0 + r0) * K + k0 + c0 * 8], &Bs[wave * 1024]);
        cp16(&Bt[(size_t)(n0 + r1) * K + k0 + c0 * 8], &Bs[wave * 1024 + 512]);
        __syncthreads();

        bf16x8 a[4], b[4];
#pragma unroll
        for (int i = 0; i < 4; i++)
            a[i] = *reinterpret_cast<const bf16x8*>(&As[((wm * 64 + i * 16 + l16) * 4 + quad) * 8]);
#pragma unroll
        for (int j = 0; j < 4; j++)
            b[j] = *reinterpret_cast<const bf16x8*>(&Bs[((wn * 64 + j * 16 + l16) * 4 + quad) * 8]);
#pragma unroll
        for (int i = 0; i < 4; i++)
#pragma unroll
            for (int j = 0; j < 4; j++)
                acc[i][j] = MFMA(a[i], b[j], acc[i][j], 0, 0, 0);
    }

#pragma unroll
    for (int i = 0; i < 4; i++) {
        int mbase = m0 + wm * 64 + i * 16 + quad * 4;
#pragma unroll
        for (int j = 0; j < 4; j++) {
            int n = n0 + wn * 64 + j * 16 + l16;
            float bv = bias[n];
#pragma unroll
            for (int r = 0; r < 4; r++)
                out[(size_t)(mbase + r) * N + n] = acc[i][j][r] + bv;
        }
    }
}

extern "C" void kernel_launch(void* const* d_in, const int* in_sizes, int n_in,
                              void* d_out, int out_size, void* d_ws, size_t ws_size,
                              hipStream_t stream) {
    const float* x      = (const float*)d_in[0];
    const float* w_qkv  = (const float*)d_in[1];
    const float* b_qkv  = (const float*)d_in[2];
    const float* w_proj = (const float*)d_in[3];
    const float* b_proj = (const float*)d_in[4];
    float* out = (float*)d_out;

    const size_t per = (size_t)BDIM * HDIM * SDIM * DDIM;  // 8388608
    u16* Qb  = (u16*)d_ws;
    u16* Kb  = Qb + per;
    u16* Vtb = Kb + per;
    u16* Ob  = Vtb + per;
    u16* Xb  = Ob;            // alias: Xb dead before attn writes Ob
    u16* WqT = Ob + per;
    u16* WpT = WqT + (size_t)3 * CDIM * CDIM;

    dim3 blk(256);
    conv_cast<<<dim3(per / (256 * 8)), blk, 0, stream>>>(x, Xb);
    conv_t<<<dim3(3 * CDIM / 64, CDIM / 64), blk, 0, stream>>>(w_qkv, WqT, CDIM, 3 * CDIM);
    conv_t<<<dim3(CDIM / 64, CDIM / 64), blk, 0, stream>>>(w_proj, WpT, CDIM, CDIM);

    gemm_qkv<<<dim3(3 * CDIM / 128, BDIM * SDIM / 128), blk, 0, stream>>>(
        Xb, WqT, b_qkv, Qb, Kb, Vtb);
    attn<<<dim3(BDIM * HDIM * (SDIM / 128)), blk, 0, stream>>>(Qb, Kb, Vtb, Ob);
    gemm_proj<<<dim3(CDIM / 128, BDIM * SDIM / 128), blk, 0, stream>>>(
        Ob, WpT, b_proj, out);
}

// Round 6
// 258.048 us; speedup vs baseline: 2.9359x; 1.2120x over previous
//
#include <hip/hip_runtime.h>

#define SDIM 2048
#define CDIM 1024
#define BDIM 4
#define HDIM 16
#define DDIM 64

// 0.125 (1/sqrt(D)) * log2(e), folded into Q so P = exp2(q.k_scaled)
#define ATT_SCALE 0.18033688011112042f

typedef __attribute__((ext_vector_type(8))) short bf16x8;
typedef __attribute__((ext_vector_type(4))) short bf16x4;
typedef __attribute__((ext_vector_type(4))) float f32x4;
typedef unsigned short u16;

#define MFMA __builtin_amdgcn_mfma_f32_16x16x32_bf16
// Compiler-only fence: pins program order of type-punned LDS store->load pairs
// (TBAA would otherwise allow hoisting the loads above the stores). Same-wave
// DS ops execute in order in HW, so no s_waitcnt semantics are needed.
#define LDS_ORDER_FENCE() __asm__ __volatile__("" ::: "memory")

__device__ __forceinline__ u16 f2b(float f) {   // RTNE
    union { float f; unsigned u; } v; v.f = f;
    unsigned r = v.u + 0x7FFFu + ((v.u >> 16) & 1u);
    return (u16)(r >> 16);
}
__device__ __forceinline__ u16 f2b_trunc(float f) {  // cheap, for P only
    union { float f; unsigned u; } v; v.f = f;
    return (u16)(v.u >> 16);
}

typedef const __attribute__((address_space(1))) unsigned int* gas_t;
typedef __attribute__((address_space(3))) unsigned int* las_t;
__device__ __forceinline__ void cp16(const void* g, void* l) {
    // 16B direct global->LDS; LDS dest = wave-uniform base + lane*16
    __builtin_amdgcn_global_load_lds((gas_t)g, (las_t)l, 16, 0, 0);
}

__device__ __forceinline__ float fast_exp2(float x) {
#if __has_builtin(__builtin_amdgcn_exp2f)
    return __builtin_amdgcn_exp2f(x);
#else
    return __exp2f(x);
#endif
}

// ---------------------------------------------------------------------------
// conv_cast: fp32 -> bf16 elementwise (x). 8 elems/thread.
// ---------------------------------------------------------------------------
__global__ __launch_bounds__(256) void conv_cast(
    const float* __restrict__ src, u16* __restrict__ dst)
{
    int i = (blockIdx.x * 256 + threadIdx.x) * 8;
    float4 a = *reinterpret_cast<const float4*>(&src[i]);
    float4 b = *reinterpret_cast<const float4*>(&src[i + 4]);
    u16 u[8];
    u[0]=f2b(a.x); u[1]=f2b(a.y); u[2]=f2b(a.z); u[3]=f2b(a.w);
    u[4]=f2b(b.x); u[5]=f2b(b.y); u[6]=f2b(b.z); u[7]=f2b(b.w);
    *reinterpret_cast<uint4*>(&dst[i]) = *reinterpret_cast<uint4*>(u);
}

// ---------------------------------------------------------------------------
// conv_t: fp32 [K][N] -> bf16 [N][K] (weight transpose-convert), 64x64 tiles.
// ---------------------------------------------------------------------------
__global__ __launch_bounds__(256) void conv_t(
    const float* __restrict__ src, u16* __restrict__ dst, int K, int N)
{
    __shared__ __align__(16) u16 t[64][72];
    const int tid = threadIdx.x;
    const int k0 = blockIdx.y * 64, n0 = blockIdx.x * 64;
#pragma unroll
    for (int it = 0; it < 4; it++) {
        int c = tid + it * 256;
        int r = c >> 4, c4 = (c & 15) * 4;
        float4 f = *reinterpret_cast<const float4*>(&src[(size_t)(k0 + r) * N + n0 + c4]);
        t[c4 + 0][r] = f2b(f.x);
        t[c4 + 1][r] = f2b(f.y);
        t[c4 + 2][r] = f2b(f.z);
        t[c4 + 3][r] = f2b(f.w);
    }
    __syncthreads();
#pragma unroll
    for (int it = 0; it < 2; it++) {
        int c = tid + it * 256;
        int r = c >> 3, c8 = (c & 7) * 8;
        *reinterpret_cast<uint4*>(&dst[(size_t)(n0 + r) * K + k0 + c8]) =
            *reinterpret_cast<const uint4*>(&t[r][c8]);
    }
}

// ---------------------------------------------------------------------------
// gemm_qkv: Xb bf16 [8192][1024] @ WqT bf16 [3072][1024]^T + b ->
//   Q (pre-scaled by ATT_SCALE), K in [B,H,S,D]; V transposed [B,H,D,S].
// V epilogue goes through an LDS transpose for coalesced global writes.
// ---------------------------------------------------------------------------
__global__ __launch_bounds__(256) void gemm_qkv(
    const u16* __restrict__ A, const u16* __restrict__ Bt,
    const float* __restrict__ bias,
    u16* __restrict__ Qb, u16* __restrict__ Kb, u16* __restrict__ Vtb)
{
    __shared__ __align__(16) u16 As[128 * 32];
    __shared__ __align__(16) u16 Bs[128 * 32];
    __shared__ __align__(16) u16 Vt[4][64 * 72];
    const int tid = threadIdx.x, lane = tid & 63, wave = tid >> 6;
    const int wm = wave >> 1, wn = wave & 1;
    const int l16 = lane & 15, quad = lane >> 4;
    const int m0 = blockIdx.y * 128, n0 = blockIdx.x * 128;
    const int K = CDIM;

    const int cl0 = wave * 128 + lane;
    const int r0 = cl0 >> 2, c0 = cl0 & 3;
    const int r1 = r0 + 16;

    f32x4 acc[4][4];
#pragma unroll
    for (int i = 0; i < 4; i++)
#pragma unroll
        for (int j = 0; j < 4; j++) acc[i][j] = (f32x4){0.f, 0.f, 0.f, 0.f};

    for (int k0 = 0; k0 < K; k0 += 32) {
        __syncthreads();
        cp16(&A [(size_t)(m0 + r0) * K + k0 + c0 * 8], &As[wave * 1024]);
        cp16(&A [(size_t)(m0 + r1) * K + k0 + c0 * 8], &As[wave * 1024 + 512]);
        cp16(&Bt[(size_t)(n0 + r0) * K + k0 + c0 * 8], &Bs[wave * 1024]);
        cp16(&Bt[(size_t)(n0 + r1) * K + k0 + c0 * 8], &Bs[wave * 1024 + 512]);
        __syncthreads();

        bf16x8 a[4], b[4];
#pragma unroll
        for (int i = 0; i < 4; i++)
            a[i] = *reinterpret_cast<const bf16x8*>(&As[((wm * 64 + i * 16 + l16) * 4 + quad) * 8]);
#pragma unroll
        for (int j = 0; j < 4; j++)
            b[j] = *reinterpret_cast<const bf16x8*>(&Bs[((wn * 64 + j * 16 + l16) * 4 + quad) * 8]);
#pragma unroll
        for (int i = 0; i < 4; i++)
#pragma unroll
            for (int j = 0; j < 4; j++)
                acc[i][j] = MFMA(a[i], b[j], acc[i][j], 0, 0, 0);
    }

    const int mm0 = m0 + wm * 64;
    const int bidx = mm0 >> 11, s0 = mm0 & 2047;

    if (n0 >= 2 * CDIM) {
        // ---- V block: LDS transpose -> coalesced [B,H,D,S] writes ----
        const int h = (n0 + wn * 64 - 2 * CDIM) >> 6;  // d0 = 0 (64-aligned)
#pragma unroll
        for (int j = 0; j < 4; j++) {
            float bv = bias[n0 + wn * 64 + j * 16 + l16];
#pragma unroll
            for (int i = 0; i < 4; i++)
#pragma unroll
                for (int r = 0; r < 4; r++)
                    Vt[wave][(j * 16 + l16) * 72 + i * 16 + quad * 4 + r] =
                        f2b(acc[i][j][r] + bv);
        }
        LDS_ORDER_FENCE();   // u16 stores -> uint4 loads: pin order vs TBAA
        const size_t gb = ((size_t)(bidx * HDIM + h)) * DDIM * SDIM;
#pragma unroll
        for (int p = 0; p < 8; p++) {
            int rr = p * 8 + (lane >> 3), ch = lane & 7;
            uint4 v = *reinterpret_cast<const uint4*>(&Vt[wave][rr * 72 + ch * 8]);
            *reinterpret_cast<uint4*>(&Vtb[gb + (size_t)rr * SDIM + s0 + ch * 8]) = v;
        }
    } else {
        // ---- Q or K block (uniform per block) ----
        const bool isK = (n0 >= CDIM);
        u16* dst = isK ? Kb : Qb;
        const float scale = isK ? 1.0f : ATT_SCALE;
#pragma unroll
        for (int j = 0; j < 4; j++) {
            int n = n0 + wn * 64 + j * 16 + l16;
            float bv = bias[n];
            int cc = n & 1023;
            int hh = cc >> 6, d = cc & 63;
            const size_t hb = ((size_t)(bidx * HDIM + hh)) * SDIM;
#pragma unroll
            for (int i = 0; i < 4; i++)
#pragma unroll
                for (int r = 0; r < 4; r++) {
                    int s = s0 + i * 16 + quad * 4 + r;
                    dst[(hb + s) * DDIM + d] = f2b((acc[i][j][r] + bv) * scale);
                }
        }
    }
}

// ---------------------------------------------------------------------------
// attn: causal flash attention, no-max-shift softmax (safe: |scores|<~9),
// row-sums via ones-column MFMA.
// Block = (b,h, 128 q-rows), 8 waves x 16 rows each (512 threads):
// short per-wave chain + 24 waves/CU (3 blocks) for latency hiding.
// K/V double-buffered via global_load_lds, ONE barrier per k-block.
// XCD swizzle: all 16 q-tiles of one (b,h) share blockIdx%8 -> same XCD L2.
// ---------------------------------------------------------------------------
__global__ __launch_bounds__(512, 6) void attn(
    const u16* __restrict__ Qb, const u16* __restrict__ Kb,
    const u16* __restrict__ Vtb, u16* __restrict__ Ob)
{
    __shared__ __align__(16) u16 Ks[2][64 * 64];
    __shared__ __align__(16) u16 Vts[2][64 * 64];
    __shared__ __align__(16) u16 Ps[8][16 * 68];   // pitch 136B: conflict-free

    const int tid = threadIdx.x;
    const int lane = tid & 63, wave = tid >> 6;       // wave 0..7
    const int l16 = lane & 15, quad = lane >> 4;
    // XCD-aware decode: bh co-located per XCD, qt descending (longest first)
    const int x = blockIdx.x;
    const int bh = (x & 7) * 8 + ((x >> 3) & 7);
    const int qt = 15 - (x >> 6);
    const int q0 = qt * 128;
    const int b = bh >> 4, h = bh & 15;
    const size_t base = (size_t)bh * (SDIM * DDIM);

    // staging chunk coords (8KB tile = 512 x 16B chunks, 1 cp16/wave/tile)
    const int cl0 = wave * 64 + lane;
    const int sr0 = cl0 >> 3, scc = cl0 & 7;
    const int sg0 = scc ^ (sr0 & 7);           // XOR-8 swizzle
    // LDS dest base for this wave's 64 chunks: u16 offset wave*512

    // Q fragments straight from global (pre-scaled by ATT_SCALE in gemm_qkv)
    const int qrow = q0 + wave * 16 + l16;
    bf16x8 aq0 = *reinterpret_cast<const bf16x8*>(&Qb[base + (size_t)qrow * DDIM + quad * 8]);
    bf16x8 aq1 = *reinterpret_cast<const bf16x8*>(&Qb[base + (size_t)qrow * DDIM + 32 + quad * 8]);

    u16* Pw = &Ps[wave][0];

    f32x4 O[4];
    f32x4 Osum = (f32x4){0.f, 0.f, 0.f, 0.f};
#pragma unroll
    for (int j = 0; j < 4; j++) O[j] = (f32x4){0.f, 0.f, 0.f, 0.f};
    // ones-column B fragment: lanes with n==0 hold 1.0bf16 in all 8 slots
    const short onev = (l16 == 0) ? (short)0x3F80 : (short)0;
    const bf16x8 bones = {onev, onev, onev, onev, onev, onev, onev, onev};

    const int nkb = (qt + 1) * 2;
    const int Arow = q0 + wave * 16;      // this wave's first q-row

    // prefetch k-block 0 into buf 0
    cp16(&Kb [base + (size_t)sr0 * DDIM + sg0 * 8], &Ks[0][wave * 512]);
    cp16(&Vtb[base + (size_t)sr0 * SDIM + sg0 * 8], &Vts[0][wave * 512]);

    for (int kbi = 0; kbi < nkb; kbi++) {
        const int cur = kbi & 1;
        const int kb = kbi * 64;
        __syncthreads();   // drains prev prefetch (vmcnt) + syncs buffer reuse
        if (kbi + 1 < nkb) {
            const int kb2 = kb + 64;
            cp16(&Kb [base + (size_t)(kb2 + sr0) * DDIM + sg0 * 8], &Ks[1 - cur][wave * 512]);
            cp16(&Vtb[base + (size_t)sr0 * SDIM + kb2 + sg0 * 8], &Vts[1 - cur][wave * 512]);
        }
        if (kb > Arow + 15) continue;     // fully masked for this wave

        const u16* Kc = &Ks[cur][0];
        const u16* Vc = &Vts[cur][0];

        // QK^T: 16 rows x 64 keys
        f32x4 sc[4];
#pragma unroll
        for (int j = 0; j < 4; j++) {
            int kr = j * 16 + l16;
            bf16x8 bk0 = *reinterpret_cast<const bf16x8*>(&Kc[(kr * 8 + ( quad      ^ (kr & 7))) * 8]);
            bf16x8 bk1 = *reinterpret_cast<const bf16x8*>(&Kc[(kr * 8 + ((quad + 4) ^ (kr & 7))) * 8]);
            f32x4 s = (f32x4){0.f, 0.f, 0.f, 0.f};
            s = MFMA(aq0, bk0, s, 0, 0, 0);
            s = MFMA(aq1, bk1, s, 0, 0, 0);
            sc[j] = s;
        }
        // causal mask (diagonal blocks only)
        if (kb + 63 > Arow) {
            const int qrel = Arow - kb;
#pragma unroll
            for (int j = 0; j < 4; j++) {
                int kk = j * 16 + l16;
#pragma unroll
                for (int r = 0; r < 4; r++)
                    sc[j][r] = (kk <= qrel + quad * 4 + r) ? sc[j][r] : -1e30f;
            }
        }
        // P = exp2(s), truncate to bf16, C-layout -> LDS
#pragma unroll
        for (int j = 0; j < 4; j++)
#pragma unroll
            for (int r = 0; r < 4; r++) {
                float p = fast_exp2(sc[j][r]);
                Pw[(quad * 4 + r) * 68 + j * 16 + l16] = f2b_trunc(p);
            }
        LDS_ORDER_FENCE();   // u16 stores -> vector loads: pin order vs TBAA
        // read back as A-fragments (bf16x4 pairs; pitch 136B = 8B-aligned)
        union { bf16x4 hp[2]; bf16x8 f; } a0u, a1u;
        a0u.hp[0] = *reinterpret_cast<const bf16x4*>(&Pw[l16 * 68 + quad * 8]);
        a0u.hp[1] = *reinterpret_cast<const bf16x4*>(&Pw[l16 * 68 + quad * 8 + 4]);
        a1u.hp[0] = *reinterpret_cast<const bf16x4*>(&Pw[l16 * 68 + 32 + quad * 8]);
        a1u.hp[1] = *reinterpret_cast<const bf16x4*>(&Pw[l16 * 68 + 32 + quad * 8 + 4]);

        // PV + free row-sum via ones column
#pragma unroll
        for (int j = 0; j < 4; j++) {
            int vr = j * 16 + l16;
            bf16x8 bv0 = *reinterpret_cast<const bf16x8*>(&Vc[(vr * 8 + ( quad      ^ (vr & 7))) * 8]);
            bf16x8 bv1 = *reinterpret_cast<const bf16x8*>(&Vc[(vr * 8 + ((quad + 4) ^ (vr & 7))) * 8]);
            O[j] = MFMA(a0u.f, bv0, O[j], 0, 0, 0);
            O[j] = MFMA(a1u.f, bv1, O[j], 0, 0, 0);
        }
        Osum = MFMA(a0u.f, bones, Osum, 0, 0, 0);
        Osum = MFMA(a1u.f, bones, Osum, 0, 0, 0);
    }

    // epilogue: normalize and store [B,S,C] bf16
#pragma unroll
    for (int r = 0; r < 4; r++) {
        float l = __shfl(Osum[r], (lane & 48));  // broadcast from l16==0 of quad
        float inv = 1.0f / l;
        int s = q0 + wave * 16 + quad * 4 + r;
#pragma unroll
        for (int j = 0; j < 4; j++)
            Ob[((size_t)(b * SDIM + s)) * CDIM + h * 64 + j * 16 + l16] =
                f2b(O[j][r] * inv);
    }
}

// ---------------------------------------------------------------------------
// gemm_proj: Ob bf16 [8192][1024] @ WpT bf16 [1024][1024]^T + b -> fp32 out.
// ---------------------------------------------------------------------------
__global__ __launch_bounds__(256) void gemm_proj(
    const u16* __restrict__ A, const u16* __restrict__ Bt,
    const float* __restrict__ bias, float* __restrict__ out)
{
    __shared__ __align__(16) u16 As[128 * 32];
    __shared__ __align__(16) u16 Bs[128 * 32];
    const int tid = threadIdx.x, lane = tid & 63, wave = tid >> 6;
    const int wm = wave >> 1, wn = wave & 1;
    const int l16 = lane & 15, quad = lane >> 4;
    const int m0 = blockIdx.y * 128, n0 = blockIdx.x * 128;
    const int K = CDIM, N = CDIM;

    const int cl0 = wave * 128 + lane;
    const int r0 = cl0 >> 2, c0 = cl0 & 3;
    const int r1 = r0 + 16;

    f32x4 acc[4][4];
#pragma unroll
    for (int i = 0; i < 4; i++)
#pragma unroll
        for (int j = 0; j < 4; j++) acc[i][j] = (f32x4){0.f, 0.f, 0.f, 0.f};

    for (int k0 = 0; k0 < K; k0 += 32) {
        __syncthreads();
        cp16(&A [(size_t)(m0 + r0) * K + k0 + c0 * 8], &As[wave * 1024]);
        cp16(&A [(size_t)(m0 + r1) * K + k0 + c0 * 8], &As[wave * 1024 + 512]);
        cp16(&Bt[(size_t)(n0 + r0) * K + k0 + c0 * 8], &Bs[wave * 1024]);
        cp16(&Bt[(size_t)(n0 + r1) * K + k0 + c0 * 8], &Bs[wave * 1024 + 512]);
        __syncthreads();

        bf16x8 a[4], b[4];
#pragma unroll
        for (int i = 0; i < 4; i++)
            a[i] = *reinterpret_cast<const bf16x8*>(&As[((wm * 64 + i * 16 + l16) * 4 + quad) * 8]);
#pragma unroll
        for (int j = 0; j < 4; j++)
            b[j] = *reinterpret_cast<const bf16x8*>(&Bs[((wn * 64 + j * 16 + l16) * 4 + quad) * 8]);
#pragma unroll
        for (int i = 0; i < 4; i++)
#pragma unroll
            for (int j = 0; j < 4; j++)
                acc[i][j] = MFMA(a[i], b[j], acc[i][j], 0, 0, 0);
    }

#pragma unroll
    for (int i = 0; i < 4; i++) {
        int mbase = m0 + wm * 64 + i * 16 + quad * 4;
#pragma unroll
        for (int j = 0; j < 4; j++) {
            int n = n0 + wn * 64 + j * 16 + l16;
            float bv = bias[n];
#pragma unroll
            for (int r = 0; r < 4; r++)
                out[(size_t)(mbase + r) * N + n] = acc[i][j][r] + bv;
        }
    }
}

extern "C" void kernel_launch(void* const* d_in, const int* in_sizes, int n_in,
                              void* d_out, int out_size, void* d_ws, size_t ws_size,
                              hipStream_t stream) {
    const float* x      = (const float*)d_in[0];
    const float* w_qkv  = (const float*)d_in[1];
    const float* b_qkv  = (const float*)d_in[2];
    const float* w_proj = (const float*)d_in[3];
    const float* b_proj = (const float*)d_in[4];
    float* out = (float*)d_out;

    const size_t per = (size_t)BDIM * HDIM * SDIM * DDIM;  // 8388608
    u16* Qb  = (u16*)d_ws;
    u16* Kb  = Qb + per;
    u16* Vtb = Kb + per;
    u16* Ob  = Vtb + per;
    u16* Xb  = Ob;            // alias: Xb dead before attn writes Ob
    u16* WqT = Ob + per;
    u16* WpT = WqT + (size_t)3 * CDIM * CDIM;

    dim3 blk(256);
    conv_cast<<<dim3(per / (256 * 8)), blk, 0, stream>>>(x, Xb);
    conv_t<<<dim3(3 * CDIM / 64, CDIM / 64), blk, 0, stream>>>(w_qkv, WqT, CDIM, 3 * CDIM);
    conv_t<<<dim3(CDIM / 64, CDIM / 64), blk, 0, stream>>>(w_proj, WpT, CDIM, CDIM);

    gemm_qkv<<<dim3(3 * CDIM / 128, BDIM * SDIM / 128), blk, 0, stream>>>(
        Xb, WqT, b_qkv, Qb, Kb, Vtb);
    attn<<<dim3(BDIM * HDIM * (SDIM / 128)), dim3(512), 0, stream>>>(Qb, Kb, Vtb, Ob);
    gemm_proj<<<dim3(CDIM / 128, BDIM * SDIM / 128), blk, 0, stream>>>(
        Ob, WpT, b_proj, out);
}

// Round 7
// 253.743 us; speedup vs baseline: 2.9857x; 1.0170x over previous
//
#include <hip/hip_runtime.h>

#define SDIM 2048
#define CDIM 1024
#define BDIM 4
#define HDIM 16
#define DDIM 64

// 0.125 (1/sqrt(D)) * log2(e), folded into Q so P = exp2(q.k_scaled)
#define ATT_SCALE 0.18033688011112042f

typedef __attribute__((ext_vector_type(8))) short bf16x8;
typedef __attribute__((ext_vector_type(4))) short bf16x4;
typedef __attribute__((ext_vector_type(4))) float f32x4;
typedef unsigned short u16;

#define MFMA __builtin_amdgcn_mfma_f32_16x16x32_bf16
// Compiler-only fence: pins program order of type-punned LDS store->load pairs
// (TBAA would otherwise allow hoisting the loads above the stores). Same-wave
// DS ops execute in order in HW, so no s_waitcnt semantics are needed.
#define LDS_ORDER_FENCE() __asm__ __volatile__("" ::: "memory")

__device__ __forceinline__ u16 f2b(float f) {   // RTNE
    union { float f; unsigned u; } v; v.f = f;
    unsigned r = v.u + 0x7FFFu + ((v.u >> 16) & 1u);
    return (u16)(r >> 16);
}
__device__ __forceinline__ u16 f2b_trunc(float f) {  // cheap, for P only
    union { float f; unsigned u; } v; v.f = f;
    return (u16)(v.u >> 16);
}

typedef const __attribute__((address_space(1))) unsigned int* gas_t;
typedef __attribute__((address_space(3))) unsigned int* las_t;
__device__ __forceinline__ void cp16(const void* g, void* l) {
    // 16B direct global->LDS; LDS dest = wave-uniform base + lane*16
    __builtin_amdgcn_global_load_lds((gas_t)g, (las_t)l, 16, 0, 0);
}

__device__ __forceinline__ float fast_exp2(float x) {
#if __has_builtin(__builtin_amdgcn_exp2f)
    return __builtin_amdgcn_exp2f(x);
#else
    return __exp2f(x);
#endif
}

// ---------------------------------------------------------------------------
// conv_cast: fp32 -> bf16 elementwise (x). 8 elems/thread.
// ---------------------------------------------------------------------------
__global__ __launch_bounds__(256) void conv_cast(
    const float* __restrict__ src, u16* __restrict__ dst)
{
    int i = (blockIdx.x * 256 + threadIdx.x) * 8;
    float4 a = *reinterpret_cast<const float4*>(&src[i]);
    float4 b = *reinterpret_cast<const float4*>(&src[i + 4]);
    u16 u[8];
    u[0]=f2b(a.x); u[1]=f2b(a.y); u[2]=f2b(a.z); u[3]=f2b(a.w);
    u[4]=f2b(b.x); u[5]=f2b(b.y); u[6]=f2b(b.z); u[7]=f2b(b.w);
    *reinterpret_cast<uint4*>(&dst[i]) = *reinterpret_cast<uint4*>(u);
}

// ---------------------------------------------------------------------------
// conv_t: fp32 [K][N] -> bf16 [N][K] (weight transpose-convert), 64x64 tiles.
// ---------------------------------------------------------------------------
__global__ __launch_bounds__(256) void conv_t(
    const float* __restrict__ src, u16* __restrict__ dst, int K, int N)
{
    __shared__ __align__(16) u16 t[64][72];
    const int tid = threadIdx.x;
    const int k0 = blockIdx.y * 64, n0 = blockIdx.x * 64;
#pragma unroll
    for (int it = 0; it < 4; it++) {
        int c = tid + it * 256;
        int r = c >> 4, c4 = (c & 15) * 4;
        float4 f = *reinterpret_cast<const float4*>(&src[(size_t)(k0 + r) * N + n0 + c4]);
        t[c4 + 0][r] = f2b(f.x);
        t[c4 + 1][r] = f2b(f.y);
        t[c4 + 2][r] = f2b(f.z);
        t[c4 + 3][r] = f2b(f.w);
    }
    __syncthreads();
#pragma unroll
    for (int it = 0; it < 2; it++) {
        int c = tid + it * 256;
        int r = c >> 3, c8 = (c & 7) * 8;
        *reinterpret_cast<uint4*>(&dst[(size_t)(n0 + r) * K + k0 + c8]) =
            *reinterpret_cast<const uint4*>(&t[r][c8]);
    }
}

// ---------------------------------------------------------------------------
// gemm_qkv: Xb bf16 [8192][1024] @ WqT bf16 [3072][1024]^T + b ->
//   Q (pre-scaled by ATT_SCALE), K in [B,H,S,D]; V transposed [B,H,D,S].
// Epilogue: chunked per-wave LDS transpose (Eb, 16x68 per wave) -> 128B-run
// coalesced dwordx4 global stores for Q, K and V. Eb is wave-private (no
// barriers); pitch 68 u16 = 136B rows (8B-aligned -> bf16x4 reads).
// ---------------------------------------------------------------------------
__global__ __launch_bounds__(256, 4) void gemm_qkv(
    const u16* __restrict__ A, const u16* __restrict__ Bt,
    const float* __restrict__ bias,
    u16* __restrict__ Qb, u16* __restrict__ Kb, u16* __restrict__ Vtb)
{
    __shared__ __align__(16) u16 As[128 * 32];
    __shared__ __align__(16) u16 Bs[128 * 32];
    __shared__ __align__(16) u16 Eb[4][16 * 68];
    const int tid = threadIdx.x, lane = tid & 63, wave = tid >> 6;
    const int wm = wave >> 1, wn = wave & 1;
    const int l16 = lane & 15, quad = lane >> 4;
    const int m0 = blockIdx.y * 128, n0 = blockIdx.x * 128;
    const int K = CDIM;

    const int cl0 = wave * 128 + lane;
    const int r0 = cl0 >> 2, c0 = cl0 & 3;
    const int r1 = r0 + 16;

    f32x4 acc[4][4];
#pragma unroll
    for (int i = 0; i < 4; i++)
#pragma unroll
        for (int j = 0; j < 4; j++) acc[i][j] = (f32x4){0.f, 0.f, 0.f, 0.f};

    for (int k0 = 0; k0 < K; k0 += 32) {
        __syncthreads();
        cp16(&A [(size_t)(m0 + r0) * K + k0 + c0 * 8], &As[wave * 1024]);
        cp16(&A [(size_t)(m0 + r1) * K + k0 + c0 * 8], &As[wave * 1024 + 512]);
        cp16(&Bt[(size_t)(n0 + r0) * K + k0 + c0 * 8], &Bs[wave * 1024]);
        cp16(&Bt[(size_t)(n0 + r1) * K + k0 + c0 * 8], &Bs[wave * 1024 + 512]);
        __syncthreads();

        bf16x8 a[4], b[4];
#pragma unroll
        for (int i = 0; i < 4; i++)
            a[i] = *reinterpret_cast<const bf16x8*>(&As[((wm * 64 + i * 16 + l16) * 4 + quad) * 8]);
#pragma unroll
        for (int j = 0; j < 4; j++)
            b[j] = *reinterpret_cast<const bf16x8*>(&Bs[((wn * 64 + j * 16 + l16) * 4 + quad) * 8]);
#pragma unroll
        for (int i = 0; i < 4; i++)
#pragma unroll
            for (int j = 0; j < 4; j++)
                acc[i][j] = MFMA(a[i], b[j], acc[i][j], 0, 0, 0);
    }

    const int mm0 = m0 + wm * 64;
    const int bidx = mm0 >> 11, s0 = mm0 & 2047;
    const int n_base = n0 + wn * 64;            // 64-aligned
    u16* eb = &Eb[wave][0];
    const int erow = lane >> 2, ec = (lane & 3) * 16;

    if (n0 >= 2 * CDIM) {
        // ---- V: chunk by d-group j; eb row = d-local (l16), col = s-local ----
        const int h = (n_base - 2 * CDIM) >> 6;
        const size_t gb = ((size_t)(bidx * HDIM + h)) * DDIM * SDIM;
#pragma unroll
        for (int j = 0; j < 4; j++) {
            float bvj = bias[n_base + j * 16 + l16];
            LDS_ORDER_FENCE();
#pragma unroll
            for (int i = 0; i < 4; i++)
#pragma unroll
                for (int r = 0; r < 4; r++)
                    eb[l16 * 68 + i * 16 + quad * 4 + r] = f2b(acc[i][j][r] + bvj);
            LDS_ORDER_FENCE();
            union { bf16x4 hp[4]; uint4 u[2]; } pk;
            pk.hp[0] = *reinterpret_cast<const bf16x4*>(&eb[erow * 68 + ec]);
            pk.hp[1] = *reinterpret_cast<const bf16x4*>(&eb[erow * 68 + ec + 4]);
            pk.hp[2] = *reinterpret_cast<const bf16x4*>(&eb[erow * 68 + ec + 8]);
            pk.hp[3] = *reinterpret_cast<const bf16x4*>(&eb[erow * 68 + ec + 12]);
            u16* gp = &Vtb[gb + (size_t)(j * 16 + erow) * SDIM + s0 + ec];
            *reinterpret_cast<uint4*>(gp)     = pk.u[0];
            *reinterpret_cast<uint4*>(gp + 8) = pk.u[1];
        }
    } else {
        // ---- Q or K: chunk by s-group i; eb row = s-local, col = d ----
        const bool isK = (n_base >= CDIM);
        u16* dst = isK ? Kb : Qb;
        const float scale = isK ? 1.0f : ATT_SCALE;
        const int hh = (n_base & 1023) >> 6;
        const size_t hb = ((size_t)(bidx * HDIM + hh)) * SDIM;
        float bvj[4];
#pragma unroll
        for (int j = 0; j < 4; j++) bvj[j] = bias[n_base + j * 16 + l16];
#pragma unroll
        for (int i = 0; i < 4; i++) {
            LDS_ORDER_FENCE();
#pragma unroll
            for (int j = 0; j < 4; j++)
#pragma unroll
                for (int r = 0; r < 4; r++)
                    eb[(quad * 4 + r) * 68 + j * 16 + l16] =
                        f2b((acc[i][j][r] + bvj[j]) * scale);
            LDS_ORDER_FENCE();
            union { bf16x4 hp[4]; uint4 u[2]; } pk;
            pk.hp[0] = *reinterpret_cast<const bf16x4*>(&eb[erow * 68 + ec]);
            pk.hp[1] = *reinterpret_cast<const bf16x4*>(&eb[erow * 68 + ec + 4]);
            pk.hp[2] = *reinterpret_cast<const bf16x4*>(&eb[erow * 68 + ec + 8]);
            pk.hp[3] = *reinterpret_cast<const bf16x4*>(&eb[erow * 68 + ec + 12]);
            const int s = s0 + i * 16 + erow;
            u16* gp = &dst[(hb + s) * DDIM + ec];
            *reinterpret_cast<uint4*>(gp)     = pk.u[0];
            *reinterpret_cast<uint4*>(gp + 8) = pk.u[1];
        }
    }
}

// ---------------------------------------------------------------------------
// attn: causal flash attention, no-max-shift softmax (safe: |scores|<~9),
// row-sums via ones-column MFMA.
// Block = (b,h, 128 q-rows), 8 waves x 16 rows each (512 threads):
// short per-wave chain + 24 waves/CU (3 blocks) for latency hiding.
// K/V double-buffered via global_load_lds, ONE barrier per k-block.
// XCD swizzle: all 16 q-tiles of one (b,h) share blockIdx%8 -> same XCD L2.
// ---------------------------------------------------------------------------
__global__ __launch_bounds__(512, 6) void attn(
    const u16* __restrict__ Qb, const u16* __restrict__ Kb,
    const u16* __restrict__ Vtb, u16* __restrict__ Ob)
{
    __shared__ __align__(16) u16 Ks[2][64 * 64];
    __shared__ __align__(16) u16 Vts[2][64 * 64];
    __shared__ __align__(16) u16 Ps[8][16 * 68];   // pitch 136B: conflict-free

    const int tid = threadIdx.x;
    const int lane = tid & 63, wave = tid >> 6;       // wave 0..7
    const int l16 = lane & 15, quad = lane >> 4;
    // XCD-aware decode: bh co-located per XCD, qt descending (longest first)
    const int x = blockIdx.x;
    const int bh = (x & 7) * 8 + ((x >> 3) & 7);
    const int qt = 15 - (x >> 6);
    const int q0 = qt * 128;
    const int b = bh >> 4, h = bh & 15;
    const size_t base = (size_t)bh * (SDIM * DDIM);

    // staging chunk coords (8KB tile = 512 x 16B chunks, 1 cp16/wave/tile)
    const int cl0 = wave * 64 + lane;
    const int sr0 = cl0 >> 3, scc = cl0 & 7;
    const int sg0 = scc ^ (sr0 & 7);           // XOR-8 swizzle

    // Q fragments straight from global (pre-scaled by ATT_SCALE in gemm_qkv)
    const int qrow = q0 + wave * 16 + l16;
    bf16x8 aq0 = *reinterpret_cast<const bf16x8*>(&Qb[base + (size_t)qrow * DDIM + quad * 8]);
    bf16x8 aq1 = *reinterpret_cast<const bf16x8*>(&Qb[base + (size_t)qrow * DDIM + 32 + quad * 8]);

    u16* Pw = &Ps[wave][0];

    f32x4 O[4];
    f32x4 Osum = (f32x4){0.f, 0.f, 0.f, 0.f};
#pragma unroll
    for (int j = 0; j < 4; j++) O[j] = (f32x4){0.f, 0.f, 0.f, 0.f};
    // ones-column B fragment: lanes with n==0 hold 1.0bf16 in all 8 slots
    const short onev = (l16 == 0) ? (short)0x3F80 : (short)0;
    const bf16x8 bones = {onev, onev, onev, onev, onev, onev, onev, onev};

    const int nkb = (qt + 1) * 2;
    const int Arow = q0 + wave * 16;      // this wave's first q-row

    // prefetch k-block 0 into buf 0
    cp16(&Kb [base + (size_t)sr0 * DDIM + sg0 * 8], &Ks[0][wave * 512]);
    cp16(&Vtb[base + (size_t)sr0 * SDIM + sg0 * 8], &Vts[0][wave * 512]);

    for (int kbi = 0; kbi < nkb; kbi++) {
        const int cur = kbi & 1;
        const int kb = kbi * 64;
        __syncthreads();   // drains prev prefetch (vmcnt) + syncs buffer reuse
        if (kbi + 1 < nkb) {
            const int kb2 = kb + 64;
            cp16(&Kb [base + (size_t)(kb2 + sr0) * DDIM + sg0 * 8], &Ks[1 - cur][wave * 512]);
            cp16(&Vtb[base + (size_t)sr0 * SDIM + kb2 + sg0 * 8], &Vts[1 - cur][wave * 512]);
        }
        if (kb > Arow + 15) continue;     // fully masked for this wave

        const u16* Kc = &Ks[cur][0];
        const u16* Vc = &Vts[cur][0];

        // QK^T: 16 rows x 64 keys
        f32x4 sc[4];
#pragma unroll
        for (int j = 0; j < 4; j++) {
            int kr = j * 16 + l16;
            bf16x8 bk0 = *reinterpret_cast<const bf16x8*>(&Kc[(kr * 8 + ( quad      ^ (kr & 7))) * 8]);
            bf16x8 bk1 = *reinterpret_cast<const bf16x8*>(&Kc[(kr * 8 + ((quad + 4) ^ (kr & 7))) * 8]);
            f32x4 s = (f32x4){0.f, 0.f, 0.f, 0.f};
            s = MFMA(aq0, bk0, s, 0, 0, 0);
            s = MFMA(aq1, bk1, s, 0, 0, 0);
            sc[j] = s;
        }
        // causal mask (diagonal blocks only)
        if (kb + 63 > Arow) {
            const int qrel = Arow - kb;
#pragma unroll
            for (int j = 0; j < 4; j++) {
                int kk = j * 16 + l16;
#pragma unroll
                for (int r = 0; r < 4; r++)
                    sc[j][r] = (kk <= qrel + quad * 4 + r) ? sc[j][r] : -1e30f;
            }
        }
        // P = exp2(s), truncate to bf16, C-layout -> LDS
#pragma unroll
        for (int j = 0; j < 4; j++)
#pragma unroll
            for (int r = 0; r < 4; r++) {
                float p = fast_exp2(sc[j][r]);
                Pw[(quad * 4 + r) * 68 + j * 16 + l16] = f2b_trunc(p);
            }
        LDS_ORDER_FENCE();   // u16 stores -> vector loads: pin order vs TBAA
        // read back as A-fragments (bf16x4 pairs; pitch 136B = 8B-aligned)
        union { bf16x4 hp[2]; bf16x8 f; } a0u, a1u;
        a0u.hp[0] = *reinterpret_cast<const bf16x4*>(&Pw[l16 * 68 + quad * 8]);
        a0u.hp[1] = *reinterpret_cast<const bf16x4*>(&Pw[l16 * 68 + quad * 8 + 4]);
        a1u.hp[0] = *reinterpret_cast<const bf16x4*>(&Pw[l16 * 68 + 32 + quad * 8]);
        a1u.hp[1] = *reinterpret_cast<const bf16x4*>(&Pw[l16 * 68 + 32 + quad * 8 + 4]);

        // PV + free row-sum via ones column
#pragma unroll
        for (int j = 0; j < 4; j++) {
            int vr = j * 16 + l16;
            bf16x8 bv0 = *reinterpret_cast<const bf16x8*>(&Vc[(vr * 8 + ( quad      ^ (vr & 7))) * 8]);
            bf16x8 bv1 = *reinterpret_cast<const bf16x8*>(&Vc[(vr * 8 + ((quad + 4) ^ (vr & 7))) * 8]);
            O[j] = MFMA(a0u.f, bv0, O[j], 0, 0, 0);
            O[j] = MFMA(a1u.f, bv1, O[j], 0, 0, 0);
        }
        Osum = MFMA(a0u.f, bones, Osum, 0, 0, 0);
        Osum = MFMA(a1u.f, bones, Osum, 0, 0, 0);
    }

    // epilogue: normalize and store [B,S,C] bf16
#pragma unroll
    for (int r = 0; r < 4; r++) {
        float l = __shfl(Osum[r], (lane & 48));  // broadcast from l16==0 of quad
        float inv = 1.0f / l;
        int s = q0 + wave * 16 + quad * 4 + r;
#pragma unroll
        for (int j = 0; j < 4; j++)
            Ob[((size_t)(b * SDIM + s)) * CDIM + h * 64 + j * 16 + l16] =
                f2b(O[j][r] * inv);
    }
}

// ---------------------------------------------------------------------------
// gemm_proj: Ob bf16 [8192][1024] @ WpT bf16 [1024][1024]^T + b -> fp32 out.
// ---------------------------------------------------------------------------
__global__ __launch_bounds__(256) void gemm_proj(
    const u16* __restrict__ A, const u16* __restrict__ Bt,
    const float* __restrict__ bias, float* __restrict__ out)
{
    __shared__ __align__(16) u16 As[128 * 32];
    __shared__ __align__(16) u16 Bs[128 * 32];
    const int tid = threadIdx.x, lane = tid & 63, wave = tid >> 6;
    const int wm = wave >> 1, wn = wave & 1;
    const int l16 = lane & 15, quad = lane >> 4;
    const int m0 = blockIdx.y * 128, n0 = blockIdx.x * 128;
    const int K = CDIM, N = CDIM;

    const int cl0 = wave * 128 + lane;
    const int r0 = cl0 >> 2, c0 = cl0 & 3;
    const int r1 = r0 + 16;

    f32x4 acc[4][4];
#pragma unroll
    for (int i = 0; i < 4; i++)
#pragma unroll
        for (int j = 0; j < 4; j++) acc[i][j] = (f32x4){0.f, 0.f, 0.f, 0.f};

    for (int k0 = 0; k0 < K; k0 += 32) {
        __syncthreads();
        cp16(&A [(size_t)(m0 + r0) * K + k0 + c0 * 8], &As[wave * 1024]);
        cp16(&A [(size_t)(m0 + r1) * K + k0 + c0 * 8], &As[wave * 1024 + 512]);
        cp16(&Bt[(size_t)(n0 + r0) * K + k0 + c0 * 8], &Bs[wave * 1024]);
        cp16(&Bt[(size_t)(n0 + r1) * K + k0 + c0 * 8], &Bs[wave * 1024 + 512]);
        __syncthreads();

        bf16x8 a[4], b[4];
#pragma unroll
        for (int i = 0; i < 4; i++)
            a[i] = *reinterpret_cast<const bf16x8*>(&As[((wm * 64 + i * 16 + l16) * 4 + quad) * 8]);
#pragma unroll
        for (int j = 0; j < 4; j++)
            b[j] = *reinterpret_cast<const bf16x8*>(&Bs[((wn * 64 + j * 16 + l16) * 4 + quad) * 8]);
#pragma unroll
        for (int i = 0; i < 4; i++)
#pragma unroll
            for (int j = 0; j < 4; j++)
                acc[i][j] = MFMA(a[i], b[j], acc[i][j], 0, 0, 0);
    }

#pragma unroll
    for (int i = 0; i < 4; i++) {
        int mbase = m0 + wm * 64 + i * 16 + quad * 4;
#pragma unroll
        for (int j = 0; j < 4; j++) {
            int n = n0 + wn * 64 + j * 16 + l16;
            float bv = bias[n];
#pragma unroll
            for (int r = 0; r < 4; r++)
                out[(size_t)(mbase + r) * N + n] = acc[i][j][r] + bv;
        }
    }
}

extern "C" void kernel_launch(void* const* d_in, const int* in_sizes, int n_in,
                              void* d_out, int out_size, void* d_ws, size_t ws_size,
                              hipStream_t stream) {
    const float* x      = (const float*)d_in[0];
    const float* w_qkv  = (const float*)d_in[1];
    const float* b_qkv  = (const float*)d_in[2];
    const float* w_proj = (const float*)d_in[3];
    const float* b_proj = (const float*)d_in[4];
    float* out = (float*)d_out;

    const size_t per = (size_t)BDIM * HDIM * SDIM * DDIM;  // 8388608
    u16* Qb  = (u16*)d_ws;
    u16* Kb  = Qb + per;
    u16* Vtb = Kb + per;
    u16* Ob  = Vtb + per;
    u16* Xb  = Ob;            // alias: Xb dead before attn writes Ob
    u16* WqT = Ob + per;
    u16* WpT = WqT + (size_t)3 * CDIM * CDIM;

    dim3 blk(256);
    conv_cast<<<dim3(per / (256 * 8)), blk, 0, stream>>>(x, Xb);
    conv_t<<<dim3(3 * CDIM / 64, CDIM / 64), blk, 0, stream>>>(w_qkv, WqT, CDIM, 3 * CDIM);
    conv_t<<<dim3(CDIM / 64, CDIM / 64), blk, 0, stream>>>(w_proj, WpT, CDIM, CDIM);

    gemm_qkv<<<dim3(3 * CDIM / 128, BDIM * SDIM / 128), blk, 0, stream>>>(
        Xb, WqT, b_qkv, Qb, Kb, Vtb);
    attn<<<dim3(BDIM * HDIM * (SDIM / 128)), dim3(512), 0, stream>>>(Qb, Kb, Vtb, Ob);
    gemm_proj<<<dim3(CDIM / 128, BDIM * SDIM / 128), blk, 0, stream>>>(
        Ob, WpT, b_proj, out);
}

// Round 8
// 246.750 us; speedup vs baseline: 3.0703x; 1.0283x over previous
//
#include <hip/hip_runtime.h>

#define SDIM 2048
#define CDIM 1024
#define BDIM 4
#define HDIM 16
#define DDIM 64

// 0.125 (1/sqrt(D)) * log2(e), folded into Q so P = exp2(q.k_scaled)
#define ATT_SCALE 0.18033688011112042f

typedef __attribute__((ext_vector_type(8))) short bf16x8;
typedef __attribute__((ext_vector_type(4))) short bf16x4;
typedef __attribute__((ext_vector_type(4))) float f32x4;
typedef unsigned short u16;

#define MFMA __builtin_amdgcn_mfma_f32_16x16x32_bf16
// Compiler-only fence: pins program order of type-punned LDS store->load pairs
// (TBAA would otherwise allow hoisting the loads above the stores). Same-wave
// DS ops execute in order in HW, so no s_waitcnt semantics are needed.
#define LDS_ORDER_FENCE() __asm__ __volatile__("" ::: "memory")

__device__ __forceinline__ u16 f2b(float f) {   // RTNE
    union { float f; unsigned u; } v; v.f = f;
    unsigned r = v.u + 0x7FFFu + ((v.u >> 16) & 1u);
    return (u16)(r >> 16);
}
__device__ __forceinline__ u16 f2b_trunc(float f) {  // cheap, for P only
    union { float f; unsigned u; } v; v.f = f;
    return (u16)(v.u >> 16);
}

typedef const __attribute__((address_space(1))) unsigned int* gas_t;
typedef __attribute__((address_space(3))) unsigned int* las_t;
__device__ __forceinline__ void cp16(const void* g, void* l) {
    // 16B direct global->LDS; LDS dest = wave-uniform base + lane*16
    __builtin_amdgcn_global_load_lds((gas_t)g, (las_t)l, 16, 0, 0);
}

__device__ __forceinline__ float fast_exp2(float x) {
#if __has_builtin(__builtin_amdgcn_exp2f)
    return __builtin_amdgcn_exp2f(x);
#else
    return __exp2f(x);
#endif
}

// ---------------------------------------------------------------------------
// prep (fused): [0,4096) conv_cast x fp32->bf16; [4096,4864) w_qkv transpose;
// [4864,5120) w_proj transpose. One launch instead of three.
// ---------------------------------------------------------------------------
__global__ __launch_bounds__(256) void prep(
    const float* __restrict__ x, const float* __restrict__ w_qkv,
    const float* __restrict__ w_proj,
    u16* __restrict__ Xb, u16* __restrict__ WqT, u16* __restrict__ WpT)
{
    __shared__ __align__(16) u16 t[64][72];
    const int bx = blockIdx.x;
    const int tid = threadIdx.x;

    if (bx < 4096) {
        // ---- conv_cast: 8 elems/thread ----
        int i = (bx * 256 + tid) * 8;
        float4 a = *reinterpret_cast<const float4*>(&x[i]);
        float4 b = *reinterpret_cast<const float4*>(&x[i + 4]);
        u16 u[8];
        u[0]=f2b(a.x); u[1]=f2b(a.y); u[2]=f2b(a.z); u[3]=f2b(a.w);
        u[4]=f2b(b.x); u[5]=f2b(b.y); u[6]=f2b(b.z); u[7]=f2b(b.w);
        *reinterpret_cast<uint4*>(&Xb[i]) = *reinterpret_cast<uint4*>(u);
        return;
    }

    // ---- conv_t: fp32 [K][N] -> bf16 [N][K], 64x64 tile ----
    const float* src; u16* dst; int N, n0, k0;
    if (bx < 4096 + 768) {
        int b2 = bx - 4096;
        src = w_qkv; dst = WqT; N = 3 * CDIM;
        n0 = (b2 % 48) * 64; k0 = (b2 / 48) * 64;
    } else {
        int b2 = bx - 4864;
        src = w_proj; dst = WpT; N = CDIM;
        n0 = (b2 % 16) * 64; k0 = (b2 / 16) * 64;
    }
    const int K = CDIM;
#pragma unroll
    for (int it = 0; it < 4; it++) {
        int c = tid + it * 256;
        int r = c >> 4, c4 = (c & 15) * 4;
        float4 f = *reinterpret_cast<const float4*>(&src[(size_t)(k0 + r) * N + n0 + c4]);
        t[c4 + 0][r] = f2b(f.x);
        t[c4 + 1][r] = f2b(f.y);
        t[c4 + 2][r] = f2b(f.z);
        t[c4 + 3][r] = f2b(f.w);
    }
    __syncthreads();
#pragma unroll
    for (int it = 0; it < 2; it++) {
        int c = tid + it * 256;
        int r = c >> 3, c8 = (c & 7) * 8;
        *reinterpret_cast<uint4*>(&dst[(size_t)(n0 + r) * K + k0 + c8]) =
            *reinterpret_cast<const uint4*>(&t[r][c8]);
    }
}

// ---------------------------------------------------------------------------
// gemm_qkv: Xb bf16 [8192][1024] @ WqT bf16 [3072][1024]^T + b ->
//   Q (pre-scaled by ATT_SCALE), K in [B,H,S,D]; V transposed [B,H,D,S].
// BK=64 tiles, XOR-8 swizzled LDS (slot = row*8 + (chunk^(row&7))):
// conflict-free b128 fragment reads; 32 MFMA per barrier-pair.
// Epilogue: chunked per-wave LDS transpose -> coalesced dwordx4 stores.
// ---------------------------------------------------------------------------
__global__ __launch_bounds__(256, 4) void gemm_qkv(
    const u16* __restrict__ A, const u16* __restrict__ Bt,
    const float* __restrict__ bias,
    u16* __restrict__ Qb, u16* __restrict__ Kb, u16* __restrict__ Vtb)
{
    __shared__ __align__(16) u16 As[128 * 64];
    __shared__ __align__(16) u16 Bs[128 * 64];
    __shared__ __align__(16) u16 Eb[4][16 * 68];
    const int tid = threadIdx.x, lane = tid & 63, wave = tid >> 6;
    const int wm = wave >> 1, wn = wave & 1;
    const int l16 = lane & 15, quad = lane >> 4;
    const int m0 = blockIdx.y * 128, n0 = blockIdx.x * 128;
    const int K = CDIM;

    const int l8 = lane & 7, lr = lane >> 3;   // staging: chunk-col, row-in-8
    const int sg = l8 ^ lr;                    // XOR-8 swizzled chunk col

    f32x4 acc[4][4];
#pragma unroll
    for (int i = 0; i < 4; i++)
#pragma unroll
        for (int j = 0; j < 4; j++) acc[i][j] = (f32x4){0.f, 0.f, 0.f, 0.f};

    for (int k0 = 0; k0 < K; k0 += 64) {
        __syncthreads();
#pragma unroll
        for (int u = 0; u < 4; u++) {
            int row = wave * 32 + u * 8 + lr;
            cp16(&A [(size_t)(m0 + row) * K + k0 + sg * 8], &As[(wave * 4 + u) * 512]);
            cp16(&Bt[(size_t)(n0 + row) * K + k0 + sg * 8], &Bs[(wave * 4 + u) * 512]);
        }
        __syncthreads();

#pragma unroll
        for (int kk = 0; kk < 2; kk++) {
            bf16x8 a[4], b[4];
#pragma unroll
            for (int i = 0; i < 4; i++) {
                int row = wm * 64 + i * 16 + l16;
                a[i] = *reinterpret_cast<const bf16x8*>(
                    &As[(row * 8 + ((kk * 4 + quad) ^ (l16 & 7))) * 8]);
            }
#pragma unroll
            for (int j = 0; j < 4; j++) {
                int row = wn * 64 + j * 16 + l16;
                b[j] = *reinterpret_cast<const bf16x8*>(
                    &Bs[(row * 8 + ((kk * 4 + quad) ^ (l16 & 7))) * 8]);
            }
#pragma unroll
            for (int i = 0; i < 4; i++)
#pragma unroll
                for (int j = 0; j < 4; j++)
                    acc[i][j] = MFMA(a[i], b[j], acc[i][j], 0, 0, 0);
        }
    }

    const int mm0 = m0 + wm * 64;
    const int bidx = mm0 >> 11, s0 = mm0 & 2047;
    const int n_base = n0 + wn * 64;            // 64-aligned
    u16* eb = &Eb[wave][0];
    const int erow = lane >> 2, ec = (lane & 3) * 16;

    if (n0 >= 2 * CDIM) {
        // ---- V: chunk by d-group j; eb row = d-local (l16), col = s-local ----
        const int h = (n_base - 2 * CDIM) >> 6;
        const size_t gb = ((size_t)(bidx * HDIM + h)) * DDIM * SDIM;
#pragma unroll
        for (int j = 0; j < 4; j++) {
            float bvj = bias[n_base + j * 16 + l16];
            LDS_ORDER_FENCE();
#pragma unroll
            for (int i = 0; i < 4; i++)
#pragma unroll
                for (int r = 0; r < 4; r++)
                    eb[l16 * 68 + i * 16 + quad * 4 + r] = f2b(acc[i][j][r] + bvj);
            LDS_ORDER_FENCE();
            union { bf16x4 hp[4]; uint4 u[2]; } pk;
            pk.hp[0] = *reinterpret_cast<const bf16x4*>(&eb[erow * 68 + ec]);
            pk.hp[1] = *reinterpret_cast<const bf16x4*>(&eb[erow * 68 + ec + 4]);
            pk.hp[2] = *reinterpret_cast<const bf16x4*>(&eb[erow * 68 + ec + 8]);
            pk.hp[3] = *reinterpret_cast<const bf16x4*>(&eb[erow * 68 + ec + 12]);
            u16* gp = &Vtb[gb + (size_t)(j * 16 + erow) * SDIM + s0 + ec];
            *reinterpret_cast<uint4*>(gp)     = pk.u[0];
            *reinterpret_cast<uint4*>(gp + 8) = pk.u[1];
        }
    } else {
        // ---- Q or K: chunk by s-group i; eb row = s-local, col = d ----
        const bool isK = (n_base >= CDIM);
        u16* dst = isK ? Kb : Qb;
        const float scale = isK ? 1.0f : ATT_SCALE;
        const int hh = (n_base & 1023) >> 6;
        const size_t hb = ((size_t)(bidx * HDIM + hh)) * SDIM;
        float bvj[4];
#pragma unroll
        for (int j = 0; j < 4; j++) bvj[j] = bias[n_base + j * 16 + l16];
#pragma unroll
        for (int i = 0; i < 4; i++) {
            LDS_ORDER_FENCE();
#pragma unroll
            for (int j = 0; j < 4; j++)
#pragma unroll
                for (int r = 0; r < 4; r++)
                    eb[(quad * 4 + r) * 68 + j * 16 + l16] =
                        f2b((acc[i][j][r] + bvj[j]) * scale);
            LDS_ORDER_FENCE();
            union { bf16x4 hp[4]; uint4 u[2]; } pk;
            pk.hp[0] = *reinterpret_cast<const bf16x4*>(&eb[erow * 68 + ec]);
            pk.hp[1] = *reinterpret_cast<const bf16x4*>(&eb[erow * 68 + ec + 4]);
            pk.hp[2] = *reinterpret_cast<const bf16x4*>(&eb[erow * 68 + ec + 8]);
            pk.hp[3] = *reinterpret_cast<const bf16x4*>(&eb[erow * 68 + ec + 12]);
            const int s = s0 + i * 16 + erow;
            u16* gp = &dst[(hb + s) * DDIM + ec];
            *reinterpret_cast<uint4*>(gp)     = pk.u[0];
            *reinterpret_cast<uint4*>(gp + 8) = pk.u[1];
        }
    }
}

// ---------------------------------------------------------------------------
// attn: causal flash attention, no-max-shift softmax (safe: |scores|<~9),
// row-sums via ones-column MFMA.
// Block = (b,h, 128 q-rows), 8 waves x 16 rows each (512 threads).
// K/V double-buffered via global_load_lds, ONE barrier per k-block.
// XCD swizzle: all 16 q-tiles of one (b,h) share blockIdx%8 -> same XCD L2.
// ---------------------------------------------------------------------------
__global__ __launch_bounds__(512, 6) void attn(
    const u16* __restrict__ Qb, const u16* __restrict__ Kb,
    const u16* __restrict__ Vtb, u16* __restrict__ Ob)
{
    __shared__ __align__(16) u16 Ks[2][64 * 64];
    __shared__ __align__(16) u16 Vts[2][64 * 64];
    __shared__ __align__(16) u16 Ps[8][16 * 68];   // pitch 136B: conflict-free

    const int tid = threadIdx.x;
    const int lane = tid & 63, wave = tid >> 6;       // wave 0..7
    const int l16 = lane & 15, quad = lane >> 4;
    // XCD-aware decode: bh co-located per XCD, qt descending (longest first)
    const int x = blockIdx.x;
    const int bh = (x & 7) * 8 + ((x >> 3) & 7);
    const int qt = 15 - (x >> 6);
    const int q0 = qt * 128;
    const int b = bh >> 4, h = bh & 15;
    const size_t base = (size_t)bh * (SDIM * DDIM);

    // staging chunk coords (8KB tile = 512 x 16B chunks, 1 cp16/wave/tile)
    const int cl0 = wave * 64 + lane;
    const int sr0 = cl0 >> 3, scc = cl0 & 7;
    const int sg0 = scc ^ (sr0 & 7);           // XOR-8 swizzle

    // Q fragments straight from global (pre-scaled by ATT_SCALE in gemm_qkv)
    const int qrow = q0 + wave * 16 + l16;
    bf16x8 aq0 = *reinterpret_cast<const bf16x8*>(&Qb[base + (size_t)qrow * DDIM + quad * 8]);
    bf16x8 aq1 = *reinterpret_cast<const bf16x8*>(&Qb[base + (size_t)qrow * DDIM + 32 + quad * 8]);

    u16* Pw = &Ps[wave][0];

    f32x4 O[4];
    f32x4 Osum = (f32x4){0.f, 0.f, 0.f, 0.f};
#pragma unroll
    for (int j = 0; j < 4; j++) O[j] = (f32x4){0.f, 0.f, 0.f, 0.f};
    // ones-column B fragment: lanes with n==0 hold 1.0bf16 in all 8 slots
    const short onev = (l16 == 0) ? (short)0x3F80 : (short)0;
    const bf16x8 bones = {onev, onev, onev, onev, onev, onev, onev, onev};

    const int nkb = (qt + 1) * 2;
    const int Arow = q0 + wave * 16;      // this wave's first q-row

    // prefetch k-block 0 into buf 0
    cp16(&Kb [base + (size_t)sr0 * DDIM + sg0 * 8], &Ks[0][wave * 512]);
    cp16(&Vtb[base + (size_t)sr0 * SDIM + sg0 * 8], &Vts[0][wave * 512]);

    for (int kbi = 0; kbi < nkb; kbi++) {
        const int cur = kbi & 1;
        const int kb = kbi * 64;
        __syncthreads();   // drains prev prefetch (vmcnt) + syncs buffer reuse
        if (kbi + 1 < nkb) {
            const int kb2 = kb + 64;
            cp16(&Kb [base + (size_t)(kb2 + sr0) * DDIM + sg0 * 8], &Ks[1 - cur][wave * 512]);
            cp16(&Vtb[base + (size_t)sr0 * SDIM + kb2 + sg0 * 8], &Vts[1 - cur][wave * 512]);
        }
        if (kb > Arow + 15) continue;     // fully masked for this wave

        const u16* Kc = &Ks[cur][0];
        const u16* Vc = &Vts[cur][0];

        // QK^T: 16 rows x 64 keys
        f32x4 sc[4];
#pragma unroll
        for (int j = 0; j < 4; j++) {
            int kr = j * 16 + l16;
            bf16x8 bk0 = *reinterpret_cast<const bf16x8*>(&Kc[(kr * 8 + ( quad      ^ (kr & 7))) * 8]);
            bf16x8 bk1 = *reinterpret_cast<const bf16x8*>(&Kc[(kr * 8 + ((quad + 4) ^ (kr & 7))) * 8]);
            f32x4 s = (f32x4){0.f, 0.f, 0.f, 0.f};
            s = MFMA(aq0, bk0, s, 0, 0, 0);
            s = MFMA(aq1, bk1, s, 0, 0, 0);
            sc[j] = s;
        }
        // causal mask (diagonal blocks only)
        if (kb + 63 > Arow) {
            const int qrel = Arow - kb;
#pragma unroll
            for (int j = 0; j < 4; j++) {
                int kk = j * 16 + l16;
#pragma unroll
                for (int r = 0; r < 4; r++)
                    sc[j][r] = (kk <= qrel + quad * 4 + r) ? sc[j][r] : -1e30f;
            }
        }
        // P = exp2(s), truncate to bf16, C-layout -> LDS
#pragma unroll
        for (int j = 0; j < 4; j++)
#pragma unroll
            for (int r = 0; r < 4; r++) {
                float p = fast_exp2(sc[j][r]);
                Pw[(quad * 4 + r) * 68 + j * 16 + l16] = f2b_trunc(p);
            }
        LDS_ORDER_FENCE();   // u16 stores -> vector loads: pin order vs TBAA
        // read back as A-fragments (bf16x4 pairs; pitch 136B = 8B-aligned)
        union { bf16x4 hp[2]; bf16x8 f; } a0u, a1u;
        a0u.hp[0] = *reinterpret_cast<const bf16x4*>(&Pw[l16 * 68 + quad * 8]);
        a0u.hp[1] = *reinterpret_cast<const bf16x4*>(&Pw[l16 * 68 + quad * 8 + 4]);
        a1u.hp[0] = *reinterpret_cast<const bf16x4*>(&Pw[l16 * 68 + 32 + quad * 8]);
        a1u.hp[1] = *reinterpret_cast<const bf16x4*>(&Pw[l16 * 68 + 32 + quad * 8 + 4]);

        // PV + free row-sum via ones column
#pragma unroll
        for (int j = 0; j < 4; j++) {
            int vr = j * 16 + l16;
            bf16x8 bv0 = *reinterpret_cast<const bf16x8*>(&Vc[(vr * 8 + ( quad      ^ (vr & 7))) * 8]);
            bf16x8 bv1 = *reinterpret_cast<const bf16x8*>(&Vc[(vr * 8 + ((quad + 4) ^ (vr & 7))) * 8]);
            O[j] = MFMA(a0u.f, bv0, O[j], 0, 0, 0);
            O[j] = MFMA(a1u.f, bv1, O[j], 0, 0, 0);
        }
        Osum = MFMA(a0u.f, bones, Osum, 0, 0, 0);
        Osum = MFMA(a1u.f, bones, Osum, 0, 0, 0);
    }

    // epilogue: normalize and store [B,S,C] bf16
#pragma unroll
    for (int r = 0; r < 4; r++) {
        float l = __shfl(Osum[r], (lane & 48));  // broadcast from l16==0 of quad
        float inv = 1.0f / l;
        int s = q0 + wave * 16 + quad * 4 + r;
#pragma unroll
        for (int j = 0; j < 4; j++)
            Ob[((size_t)(b * SDIM + s)) * CDIM + h * 64 + j * 16 + l16] =
                f2b(O[j][r] * inv);
    }
}

// ---------------------------------------------------------------------------
// gemm_proj: Ob bf16 [8192][1024] @ WpT bf16 [1024][1024]^T + b -> fp32 out.
// BK=64 + XOR-8 swizzle (same structure as gemm_qkv).
// ---------------------------------------------------------------------------
__global__ __launch_bounds__(256, 4) void gemm_proj(
    const u16* __restrict__ A, const u16* __restrict__ Bt,
    const float* __restrict__ bias, float* __restrict__ out)
{
    __shared__ __align__(16) u16 As[128 * 64];
    __shared__ __align__(16) u16 Bs[128 * 64];
    const int tid = threadIdx.x, lane = tid & 63, wave = tid >> 6;
    const int wm = wave >> 1, wn = wave & 1;
    const int l16 = lane & 15, quad = lane >> 4;
    const int m0 = blockIdx.y * 128, n0 = blockIdx.x * 128;
    const int K = CDIM, N = CDIM;

    const int l8 = lane & 7, lr = lane >> 3;
    const int sg = l8 ^ lr;

    f32x4 acc[4][4];
#pragma unroll
    for (int i = 0; i < 4; i++)
#pragma unroll
        for (int j = 0; j < 4; j++) acc[i][j] = (f32x4){0.f, 0.f, 0.f, 0.f};

    for (int k0 = 0; k0 < K; k0 += 64) {
        __syncthreads();
#pragma unroll
        for (int u = 0; u < 4; u++) {
            int row = wave * 32 + u * 8 + lr;
            cp16(&A [(size_t)(m0 + row) * K + k0 + sg * 8], &As[(wave * 4 + u) * 512]);
            cp16(&Bt[(size_t)(n0 + row) * K + k0 + sg * 8], &Bs[(wave * 4 + u) * 512]);
        }
        __syncthreads();

#pragma unroll
        for (int kk = 0; kk < 2; kk++) {
            bf16x8 a[4], b[4];
#pragma unroll
            for (int i = 0; i < 4; i++) {
                int row = wm * 64 + i * 16 + l16;
                a[i] = *reinterpret_cast<const bf16x8*>(
                    &As[(row * 8 + ((kk * 4 + quad) ^ (l16 & 7))) * 8]);
            }
#pragma unroll
            for (int j = 0; j < 4; j++) {
                int row = wn * 64 + j * 16 + l16;
                b[j] = *reinterpret_cast<const bf16x8*>(
                    &Bs[(row * 8 + ((kk * 4 + quad) ^ (l16 & 7))) * 8]);
            }
#pragma unroll
            for (int i = 0; i < 4; i++)
#pragma unroll
                for (int j = 0; j < 4; j++)
                    acc[i][j] = MFMA(a[i], b[j], acc[i][j], 0, 0, 0);
        }
    }

#pragma unroll
    for (int i = 0; i < 4; i++) {
        int mbase = m0 + wm * 64 + i * 16 + quad * 4;
#pragma unroll
        for (int j = 0; j < 4; j++) {
            int n = n0 + wn * 64 + j * 16 + l16;
            float bv = bias[n];
#pragma unroll
            for (int r = 0; r < 4; r++)
                out[(size_t)(mbase + r) * N + n] = acc[i][j][r] + bv;
        }
    }
}

extern "C" void kernel_launch(void* const* d_in, const int* in_sizes, int n_in,
                              void* d_out, int out_size, void* d_ws, size_t ws_size,
                              hipStream_t stream) {
    const float* x      = (const float*)d_in[0];
    const float* w_qkv  = (const float*)d_in[1];
    const float* b_qkv  = (const float*)d_in[2];
    const float* w_proj = (const float*)d_in[3];
    const float* b_proj = (const float*)d_in[4];
    float* out = (float*)d_out;

    const size_t per = (size_t)BDIM * HDIM * SDIM * DDIM;  // 8388608
    u16* Qb  = (u16*)d_ws;
    u16* Kb  = Qb + per;
    u16* Vtb = Kb + per;
    u16* Ob  = Vtb + per;
    u16* Xb  = Ob;            // alias: Xb dead before attn writes Ob
    u16* WqT = Ob + per;
    u16* WpT = WqT + (size_t)3 * CDIM * CDIM;

    dim3 blk(256);
    prep<<<dim3(4096 + 768 + 256), blk, 0, stream>>>(x, w_qkv, w_proj, Xb, WqT, WpT);

    gemm_qkv<<<dim3(3 * CDIM / 128, BDIM * SDIM / 128), blk, 0, stream>>>(
        Xb, WqT, b_qkv, Qb, Kb, Vtb);
    attn<<<dim3(BDIM * HDIM * (SDIM / 128)), dim3(512), 0, stream>>>(Qb, Kb, Vtb, Ob);
    gemm_proj<<<dim3(CDIM / 128, BDIM * SDIM / 128), blk, 0, stream>>>(
        Ob, WpT, b_proj, out);
}